// Round 12
// baseline (2016.129 us; speedup 1.0000x reference)
//
#include <hip/hip_runtime.h>

typedef unsigned short u16;
typedef unsigned int   u32;
typedef __attribute__((ext_vector_type(8))) __bf16 bfrag;   // 8 bf16 = 4 VGPR
typedef __attribute__((ext_vector_type(4))) float  f32x4;
typedef __attribute__((ext_vector_type(2))) u32    u32x2;
typedef __attribute__((ext_vector_type(4))) u32    u32x4;

#define DEVI static __device__ __forceinline__

// ---- ALL cross-visible global writes are sc0sc1 (write-through to LLC).
// ---- ALL reads are plain cached loads. Correctness: no global address is
// ---- written-after-cached-read within a launch (slot rotation + launch-
// ---- boundary cache invalidation), so no fences/cache-ops are needed.
// ---- Cross-block ordering: sc store -> vmcnt(0) -> LLC atomic counter;
// ---- consumer polls counter then cached-reads (fresh address).
#define ST2SC(p, v)    asm volatile("global_store_short %0, %1, off sc0 sc1"   :: "v"(p), "v"(v) : "memory")
#define ST4SC(p, v)    asm volatile("global_store_dword %0, %1, off sc0 sc1"   :: "v"(p), "v"(v) : "memory")
#define ST8SC(p, v)    asm volatile("global_store_dwordx2 %0, %1, off sc0 sc1" :: "v"(p), "v"(v) : "memory")
#define ST16SC(p, v)   asm volatile("global_store_dwordx4 %0, %1, off sc0 sc1" :: "v"(p), "v"(v) : "memory")
#define VMFLUSH()      asm volatile("s_waitcnt vmcnt(0)" ::: "memory")

// ---------------- geometry ----------------
// T=32 B=64 S=64 E=512 H=1024 L=2 (4H=4096)
constexpr long OUT_OFF = 0;         // 32*64*1024
constexpr long HT_OFF  = 2097152;
constexpr long CT_OFF  = 2228224;
constexpr long AS_OFF  = 2359296;
constexpr long AC_OFF  = 2490368;

// ---------------- workspace layout (bytes) ----------------
constexpr long WAO_O   = 0;          // attn_out bf16 [1024][2048] (4MB) - dead after prologue
constexpr long CTX_O   = 4194304;    // ctx (8MB) - dead after S1
constexpr long OFR_O   = 0;          // OF slots 1..32  [0, 4MB)
constexpr long H0R_O   = 4194304;    // H0 slots 1..32
constexpr long H1R_O   = 8388608;    // H1 slots 1..32
constexpr long WAI_O   = 12582912;   // attn_in^T bf16 (2MB)
constexpr long WC_O    = 14680064;   // copy_in^T bf16 (2MB)
constexpr long CTXW_O  = 16777216;   // ctx @ Wai (8MB)
constexpr long CTXWC_O = 25165824;   // ctx @ Wc  (8MB)
constexpr long CTXOT_O = 33554432;   // (ctx @ Waoc)^T [b][j][s] (8MB)
constexpr long EBF_O   = 41943040;   // emb frag-major (2MB)
constexpr long OF0_O   = 44040192;   // OF slot 0 (128KB)
constexpr long H00_O   = 44171264;   // H0 slot 0
constexpr long H10_O   = 44302336;   // H1 slot 0
constexpr long AB_O    = 44433408;   // a f32 [32 t][64 b][64 s] = 512KB
constexpr long AFLAG_O = 44957696;   // a-ready flags [32 t][64 b] u32 = 8KB
constexpr long H0C_O   = 44965888;   // h0 chunk counters [33 slot][32 chunk] 64B-spaced = 66KB
constexpr long H1C_O   = 45033472;   // h1 chunk counters
constexpr long OFC_O   = 45101056;   // OF chunk counters
constexpr long BAR_O   = 45168640;   // setup barrier flags (2KB)
// memset region: [AB_O, BAR_O+2048) = 737280 bytes

// LDS layout (dynamic, 160256 B)
constexpr int W0LDS_O = 0;        // [16 rows][2560] bf16 swizzled = 81920
constexpr int W1LDS_O = 81920;    // [16 rows][2048] bf16 swizzled = 65536
constexpr int SCR_O   = 147456;   // 8 slots x 272 f32 = 8704
constexpr int SCR2_O  = 156160;   // 4096 B

struct KParams {
  const int* input; const float* h0; const float* c0; const float* context;
  const float* init_output; const float* embedding;
  const float* W_ih0; const float* W_hh0; const float* b0;
  const float* W_ih1; const float* W_hh1; const float* b1;
  const float* attn_in; const float* attn_out; const float* copy_in;
  float* out; char* ws;
};

// ---------------- small helpers ----------------
DEVI float bf2f(u16 u) { u32 x = ((u32)u) << 16; return __builtin_bit_cast(float, x); }
DEVI u16 f2bf(float f) {
  u32 x = __builtin_bit_cast(u32, f);
  u32 r = x + 0x7fffu + ((x >> 16) & 1u);   // RNE
  return (u16)(r >> 16);
}
DEVI void cvtc_sc(const float* s, char* d) {
  float4 v = *(const float4*)s;
  u32x2 u;
  u[0] = (u32)f2bf(v.x) | ((u32)f2bf(v.y) << 16);
  u[1] = (u32)f2bf(v.z) | ((u32)f2bf(v.w) << 16);
  ST8SC(d, u);
}
DEVI float sigm(float x)  { return 1.f / (1.f + __expf(-x)); }
DEVI float tanh_(float x) { return 1.f - 2.f / (__expf(2.f * x) + 1.f); }
DEVI f32x4 mfma16(bfrag a, bfrag b, f32x4 c) {
  return __builtin_amdgcn_mfma_f32_16x16x32_bf16(a, b, c, 0, 0, 0);
}
DEVI u32 fragoff(int m, int k) {
  return (u32)((((k >> 5) * 4 + (m >> 4)) * 64 + ((k >> 3) & 3) * 16 + (m & 15)) * 16 + (k & 7) * 2);
}
DEVI char* of_slot(char* w, int s) { return w + (s ? OFR_O + (long)(s - 1) * 131072 : OF0_O); }
DEVI char* h0_slot(char* w, int s) { return w + (s ? H0R_O + (long)(s - 1) * 131072 : H00_O); }
DEVI char* h1_slot(char* w, int s) { return w + (s ? H1R_O + (long)(s - 1) * 131072 : H10_O); }

// chunk counters: 64B-spaced u32 per (slot, chunk)
DEVI u32* cntb(char* w, long base, int slot) { return (u32*)(w + base + (long)slot * 2048); }
DEVI void cnt_add(u32* c) {
  (void)__hip_atomic_fetch_add(c, 1u, __ATOMIC_RELAXED, __HIP_MEMORY_SCOPE_AGENT);
}
// wave-collective poll: chunks [c0, c0+n), n in {4,16,32} (pow2); target 8
template<int N>
DEVI void poll_chunks(const u32* base, int c0) {
  const int lane = threadIdx.x & 63;
  const u32* p = base + (u32)(c0 + (lane & (N - 1))) * 16;
  for (;;) {
    u32 v = __hip_atomic_load(p, __ATOMIC_RELAXED, __HIP_MEMORY_SCOPE_AGENT);
    if (__all(v >= 8u)) break;
  }
}

// ---------------- setup barrier (2 uses) ----------------
DEVI void pollflags(u32* flags, u32 gen) {
  int t = threadIdx.x;   // < 64
  for (;;) {
    u32 a = __hip_atomic_load(&flags[t],       __ATOMIC_RELAXED, __HIP_MEMORY_SCOPE_AGENT);
    u32 b = __hip_atomic_load(&flags[64 + t],  __ATOMIC_RELAXED, __HIP_MEMORY_SCOPE_AGENT);
    u32 c = __hip_atomic_load(&flags[128 + t], __ATOMIC_RELAXED, __HIP_MEMORY_SCOPE_AGENT);
    u32 d = __hip_atomic_load(&flags[192 + t], __ATOMIC_RELAXED, __HIP_MEMORY_SCOPE_AGENT);
    if (__all((a >= gen) && (b >= gen) && (c >= gen) && (d >= gen))) break;
  }
}
DEVI void gsync_fence(u32* flags, u32 gen) {
  __syncthreads();
  if (threadIdx.x == 0) {
    __builtin_amdgcn_fence(__ATOMIC_RELEASE, "agent");
    __hip_atomic_store(&flags[blockIdx.x], gen, __ATOMIC_RELAXED, __HIP_MEMORY_SCOPE_AGENT);
  }
  if (threadIdx.x < 64) pollflags(flags, gen);
  if (threadIdx.x == 0) __builtin_amdgcn_fence(__ATOMIC_ACQUIRE, "agent");
  __syncthreads();
}

// ---------------- gate-GEMM segment ----------------
template<int N4>
DEVI void gseg(f32x4& acc, const char* Af, int kkA0, int mt, int lane,
               const char* W, int wRowK, int kkW0, int brow, int ke) {
  const u32 sw = (u32)((brow & 7) << 4);
#pragma unroll
  for (int g = 0; g < N4; ++g) {
#pragma unroll
    for (int q = 0; q < 4; ++q) {
      const char* pa = Af + ((((kkA0 + g * 4 + q) * 4 + mt) * 64 + lane) << 4);
      bfrag av = *(const bfrag*)pa;
      int kkW = kkW0 + g * 4 + q;
      u32 off = ((u32)(brow * wRowK + kkW * 32 + ke) * 2) ^ sw;
      acc = mfma16(av, *(const bfrag*)(W + off), acc);
    }
  }
}

DEVI void scr_store(float* scr, int slot, f32x4 acc) {
  const int lane = threadIdx.x & 63;
#pragma unroll
  for (int r = 0; r < 4; ++r)
    scr[slot * 272 + ((lane >> 4) * 4 + r) * 17 + (lane & 15)] = acc[r];
}

// LSTM pointwise: threads 0..63; c-state in registers; one 8B sc h-store
DEVI void pointwise64(int bid, const float* scr, const float* bias, float (&cst)[4], char* hfrag) {
  const int m = threadIdx.x;            // < 64
  const int mt = m >> 4, ml = m & 15;
  u32 hp0 = 0, hp1 = 0;
#pragma unroll
  for (int u = 0; u < 4; ++u) {
    const int j = bid * 4 + u;
    float g0 = scr[(mt*2)*272 + ml*17 + u]      + scr[(mt*2+1)*272 + ml*17 + u]      + bias[j];
    float g1 = scr[(mt*2)*272 + ml*17 + 4 + u]  + scr[(mt*2+1)*272 + ml*17 + 4 + u]  + bias[1024 + j];
    float g2 = scr[(mt*2)*272 + ml*17 + 8 + u]  + scr[(mt*2+1)*272 + ml*17 + 8 + u]  + bias[2048 + j];
    float g3 = scr[(mt*2)*272 + ml*17 + 12 + u] + scr[(mt*2+1)*272 + ml*17 + 12 + u] + bias[3072 + j];
    float cn = sigm(g1) * cst[u] + sigm(g0) * tanh_(g2);
    cst[u] = cn;
    u32 hb = (u32)f2bf(sigm(g3) * tanh_(cn));
    if (u == 0) hp0 = hb; else if (u == 1) hp0 |= hb << 16;
    else if (u == 2) hp1 = hb; else hp1 |= hb << 16;
  }
  u32x2 v; v[0] = hp0; v[1] = hp1;
  ST8SC(hfrag + fragoff(m, bid * 4), v);
}

// copy-attention for one (batch, step)
DEVI void copyattn_step(int b, int tau, const u16* CtxWc, const float* outp,
                        float* xch, float* dout) {
  const int tid = threadIdx.x, lane = tid & 63, w = tid >> 6;
  float ov[16];
  {
    const float4* op = (const float4*)(outp + (long)tau * 65536 + b * 1024 + lane * 16);
#pragma unroll
    for (int i = 0; i < 4; ++i) {
      float4 v = op[i];
      ov[4 * i] = v.x; ov[4 * i + 1] = v.y; ov[4 * i + 2] = v.z; ov[4 * i + 3] = v.w;
    }
  }
  const u16* cwb = CtxWc + (long)b * 65536;
#pragma unroll
  for (int si = 0; si < 8; ++si) {
    int s = w * 8 + si;
    const u32* u = (const u32*)(cwb + (long)s * 1024 + lane * 16);
    float acc = 0.f;
#pragma unroll
    for (int i = 0; i < 8; ++i) {
      u32 x = u[i];
      acc += ov[2 * i] * bf2f((u16)(x & 0xffff));
      acc += ov[2 * i + 1] * bf2f((u16)(x >> 16));
    }
#pragma unroll
    for (int off = 32; off; off >>= 1) acc += __shfl_down(acc, off, 64);
    if (lane == 0) xch[s] = acc;
  }
  __syncthreads();
  if (w == 0) {
    float v = xch[lane];
    float mx = v;
#pragma unroll
    for (int off = 32; off; off >>= 1) mx = fmaxf(mx, __shfl_xor(mx, off, 64));
    float e = __expf(v - mx);
    float sm = e;
#pragma unroll
    for (int off = 32; off; off >>= 1) sm += __shfl_xor(sm, off, 64);
    dout[AC_OFF + (long)tau * 4096 + b * 64 + lane] = e / sm;
  }
}

// setup GEMMs (sc stores)
DEVI void ctxw_gemm(int mt, const u16* Ctx, const u16* Wm, u16* dst) {
  const int tid = threadIdx.x, lane = tid & 63, w = tid >> 6;
  const int arow = mt * 16 + (lane & 15);
  const int ke = (lane >> 4) * 8;
#pragma unroll
  for (int i = 0; i < 8; ++i) {
    int nt = w * 8 + i;
    const u16* A = Ctx + (long)arow * 1024 + ke;
    const u16* B = Wm + (long)(nt * 16 + (lane & 15)) * 1024 + ke;
    f32x4 acc = {0.f, 0.f, 0.f, 0.f};
    for (int kk = 0; kk < 1024; kk += 32)
      acc = mfma16(*(const bfrag*)(A + kk), *(const bfrag*)(B + kk), acc);
#pragma unroll
    for (int r = 0; r < 4; ++r)
      ST2SC((char*)(dst + (long)(mt * 16 + (lane >> 4) * 4 + r) * 1024 + nt * 16 + (lane & 15)),
            (u32)f2bf(acc[r]));
  }
}
DEVI void ctxo_gemm(int bid, const u16* Ctx, const u16* Wao, u16* dst) {
  const int tid = threadIdx.x, lane = tid & 63, w = tid >> 6;
  const int arow = bid * 16 + (lane & 15);
  const int ke = (lane >> 4) * 8;
  const int b = bid >> 2, s0 = (bid & 3) * 16 + (lane >> 4) * 4;
#pragma unroll
  for (int i = 0; i < 8; ++i) {
    int nt = w * 8 + i;
    int j = nt * 16 + (lane & 15);
    const u16* A = Ctx + (long)arow * 1024 + ke;
    const u16* B = Wao + (long)j * 2048 + ke;
    f32x4 acc = {0.f, 0.f, 0.f, 0.f};
    for (int kk = 0; kk < 1024; kk += 32)
      acc = mfma16(*(const bfrag*)(A + kk), *(const bfrag*)(B + kk), acc);
    u32x2 q;
    q[0] = (u32)f2bf(acc[0]) | ((u32)f2bf(acc[1]) << 16);
    q[1] = (u32)f2bf(acc[2]) | ((u32)f2bf(acc[3]) << 16);
    ST8SC((char*)(dst + ((long)(b * 1024 + j) * 64 + s0)), q);
  }
}

// P4 tile: P4h (h1 @ Wao_h) + P4c (a @ CtxOT + h1half -> out, OF(t+1))
DEVI void p4_tile(int t, int mt, int nt, const bfrag (&waoreg)[4],
                  const char* H1n, char* wsb, const u16* CtxOT,
                  float* scr, float* scr2, float* outp) {
  const int tid = threadIdx.x, lane = tid & 63, w = tid >> 6;
  // P4h: poll h1 chunks this wave reads, then 4 MFMA
  poll_chunks<4>(cntb(wsb, H1C_O, t + 1), w * 4);
  {
    bfrag h0_ = *(const bfrag*)(H1n + ((((w * 4 + 0) * 4 + mt) * 64 + lane) << 4));
    bfrag h1_ = *(const bfrag*)(H1n + ((((w * 4 + 1) * 4 + mt) * 64 + lane) << 4));
    bfrag h2_ = *(const bfrag*)(H1n + ((((w * 4 + 2) * 4 + mt) * 64 + lane) << 4));
    bfrag h3_ = *(const bfrag*)(H1n + ((((w * 4 + 3) * 4 + mt) * 64 + lane) << 4));
    f32x4 a4 = {0.f, 0.f, 0.f, 0.f};
    a4 = mfma16(h0_, waoreg[0], a4);
    a4 = mfma16(h1_, waoreg[1], a4);
    a4 = mfma16(h2_, waoreg[2], a4);
    a4 = mfma16(h3_, waoreg[3], a4);
    scr_store(scr, w, a4);
  }
  // wait for a(t) of this tile's batches
  char* ABt = wsb + AB_O + (long)t * 16384;
  if (tid < 16) {
    const u32* fp = (const u32*)(wsb + AFLAG_O + ((u32)t * 64 + mt * 16 + tid) * 4);
    while (__hip_atomic_load(fp, __ATOMIC_RELAXED, __HIP_MEMORY_SCOPE_AGENT) == 0) {}
  }
  __syncthreads();
  {
    int b0i = tid >> 6, s0i = tid & 63;
    int b1i = (tid + 512) >> 6;
    scr2[tid]       = *(const float*)(ABt + (u32)(((mt * 16 + b0i) * 64 + s0i)) * 4);
    scr2[tid + 512] = *(const float*)(ABt + (u32)(((mt * 16 + b1i) * 64 + s0i)) * 4);
  }
  __syncthreads();
  const int pair = tid >> 1, half = tid & 1;
  const int m_l = pair >> 4, j_l = pair & 15;
  const int b = mt * 16 + m_l, j = nt * 16 + j_l;
  const u32* cp = (const u32*)(CtxOT + ((long)(b * 1024 + j) * 64 + half * 32));
  const float* al = scr2 + m_l * 64 + half * 32;
  float acc = 0.f;
#pragma unroll
  for (int i = 0; i < 16; ++i) {
    u32 x = cp[i];
    acc += al[2 * i] * bf2f((u16)(x & 0xffff));
    acc += al[2 * i + 1] * bf2f((u16)(x >> 16));
  }
  float v = acc + __shfl_xor(acc, 1, 64);
  if (half == 0) {
    float h1p = 0.f;
#pragma unroll
    for (int q = 0; q < 8; ++q) h1p += scr[q * 272 + m_l * 17 + j_l];
    v = tanh_(v + h1p);
    ST4SC((char*)(outp + (long)t * 65536 + b * 1024 + j), __builtin_bit_cast(u32, v));
    u32 hv = (u32)f2bf(v);
    ST2SC(of_slot(wsb, t + 1) + fragoff(b, j), hv);
  }
  VMFLUSH();
  __syncthreads();
  if (tid == 0) cnt_add(cntb(wsb, OFC_O, t + 1) + (nt >> 1) * 16);
}

// ---------------- the kernel ----------------
__global__ __launch_bounds__(512, 1) void decoder_kernel(KParams p) {
  extern __shared__ char smem[];
  char*  W0   = smem + W0LDS_O;
  char*  W1   = smem + W1LDS_O;
  float* scr  = (float*)(smem + SCR_O);
  float* scr2 = (float*)(smem + SCR2_O);

  char* wsb = p.ws;
  u16* Wao   = (u16*)(wsb + WAO_O);
  u16* Wai   = (u16*)(wsb + WAI_O);
  u16* Wc    = (u16*)(wsb + WC_O);
  u16* Ctx   = (u16*)(wsb + CTX_O);
  u16* CtxW  = (u16*)(wsb + CTXW_O);
  u16* CtxWc = (u16*)(wsb + CTXWC_O);
  u16* CtxOT = (u16*)(wsb + CTXOT_O);
  u32* bar   = (u32*)(wsb + BAR_O);

  const int bid = blockIdx.x, tid = threadIdx.x;
  const int lane = tid & 63, w = tid >> 6;
  const long gtid = (long)bid * 512 + tid, NT = 256l * 512;
  u32 gen = 1;

  // ---- S0-pre: LDS-tiled transposes of attn_in / copy_in ----
  {
    float* tile = (float*)smem;
    for (int pass = 0; pass < 2; ++pass) {
      const float* src = pass ? p.copy_in : p.attn_in;
      u16* dst = pass ? Wc : Wai;
      int tr = bid >> 4, tc = bid & 15;
      {
        int r = tid >> 3, c = (tid & 7) * 8;
        const float4* s4 = (const float4*)(src + (long)(tr * 64 + r) * 1024 + tc * 64 + c);
        float4 a = s4[0], b = s4[1];
        float* tp = tile + r * 69 + c;
        tp[0] = a.x; tp[1] = a.y; tp[2] = a.z; tp[3] = a.w;
        tp[4] = b.x; tp[5] = b.y; tp[6] = b.z; tp[7] = b.w;
      }
      __syncthreads();
      {
        int r2 = tid >> 3, c2 = (tid & 7) * 8;
        u32x4 q;
#pragma unroll
        for (int i = 0; i < 4; ++i) {
          float lo = tile[(c2 + 2 * i) * 69 + r2];
          float hi = tile[(c2 + 2 * i + 1) * 69 + r2];
          q[i] = (u32)f2bf(lo) | ((u32)f2bf(hi) << 16);
        }
        ST16SC((char*)(dst + (long)(tc * 64 + r2) * 1024 + tr * 64 + c2), q);
      }
      __syncthreads();
    }
  }

  // ---- S0a: per-block weight slices -> LDS ----
  for (int i = tid; i < 5120; i += 512) {
    int row = i / 320, k = (i % 320) * 8;
    int R = (row >> 2) * 1024 + bid * 4 + (row & 3);
    const float* src = (k < 1536) ? (p.W_ih0 + (long)R * 1536 + k)
                                  : (p.W_hh0 + (long)R * 1024 + (k - 1536));
    float4 a = *(const float4*)src, b = *(const float4*)(src + 4);
    uint4 q;
    q.x = (u32)f2bf(a.x) | ((u32)f2bf(a.y) << 16);
    q.y = (u32)f2bf(a.z) | ((u32)f2bf(a.w) << 16);
    q.z = (u32)f2bf(b.x) | ((u32)f2bf(b.y) << 16);
    q.w = (u32)f2bf(b.z) | ((u32)f2bf(b.w) << 16);
    u32 off = ((u32)(row * 2560 + k) * 2) ^ ((u32)((row & 7) << 4));
    *(uint4*)(W0 + off) = q;
  }
  for (int i = tid; i < 4096; i += 512) {
    int row = i / 256, k = (i % 256) * 8;
    int R = (row >> 2) * 1024 + bid * 4 + (row & 3);
    const float* src = (k < 1024) ? (p.W_ih1 + (long)R * 1024 + k)
                                  : (p.W_hh1 + (long)R * 1024 + (k - 1024));
    float4 a = *(const float4*)src, b = *(const float4*)(src + 4);
    uint4 q;
    q.x = (u32)f2bf(a.x) | ((u32)f2bf(a.y) << 16);
    q.y = (u32)f2bf(a.z) | ((u32)f2bf(a.w) << 16);
    q.z = (u32)f2bf(b.x) | ((u32)f2bf(b.y) << 16);
    q.w = (u32)f2bf(b.z) | ((u32)f2bf(b.w) << 16);
    u32 off = ((u32)(row * 2048 + k) * 2) ^ ((u32)((row & 7) << 4));
    *(uint4*)(W1 + off) = q;
  }

  // ---- S0b: global conversions (all sc stores) ----
  for (long i = gtid; i < 524288; i += NT) cvtc_sc(p.attn_out + i * 4, (char*)(Wao + i * 4));
  for (long i = gtid; i < 1048576; i += NT) {
    long b = i >> 14, s = (i >> 8) & 63, kq = i & 255;
    cvtc_sc(p.context + ((s * 64 + b) * 1024 + kq * 4), (char*)(Ctx + i * 4));
  }
  for (long i = gtid; i < 262144; i += NT) {
    long row = i >> 7; long t = row >> 6, b = row & 63;
    long k0 = (i & 127) * 4;
    long tok = p.input[row];
    cvtc_sc(p.embedding + tok * 512 + k0, wsb + EBF_O + t * 65536 + fragoff((int)b, (int)k0));
  }
  for (long i = gtid; i < 16384; i += NT) {
    long b = i >> 8, k0 = (i & 255) * 4;
    cvtc_sc(p.init_output + i * 4, of_slot(wsb, 0) + fragoff((int)b, (int)k0));
  }
  for (long i = gtid; i < 32768; i += NT) {
    long l = i >> 14, rem = i & 16383, b = rem >> 8, k0 = (rem & 255) * 4;
    cvtc_sc(p.h0 + i * 4, (l ? h1_slot(wsb, 0) : h0_slot(wsb, 0)) + fragoff((int)b, (int)k0));
  }

  // ---- c-state -> registers ----
  float cR0[4] = {0.f, 0.f, 0.f, 0.f}, cR1[4] = {0.f, 0.f, 0.f, 0.f};
  if (tid < 64) {
#pragma unroll
    for (int u = 0; u < 4; ++u) {
      cR0[u] = p.c0[(long)tid * 1024 + bid * 4 + u];
      cR1[u] = p.c0[65536 + (long)tid * 1024 + bid * 4 + u];
    }
  }

  gsync_fence(bar, gen); ++gen;

  // ---- S1: attention tables ----
  ctxw_gemm(bid, Ctx, Wai, CtxW);
  ctxw_gemm(bid, Ctx, Wc, CtxWc);
  ctxo_gemm(bid, Ctx, Wao, CtxOT);
  gsync_fence(bar, gen); ++gen;

  // ---- role assignment ----
  // blocks 0..63: P3 (batch = bid).  blocks 64..255: P4 tiles.
  // tile tau: vidx=tau>>3, mt=vidx>>3, nt=(tau&7)*8+(vidx&7).
  // block bid>=64: tile1 = bid-64; tile2 (if bid<128) = tile1+192 (same nt, mt+3).
  const bool isP3 = bid < 64;
  const int tbase = bid - 64;
  const bool dual = !isP3 && tbase < 64;
  int mtP4 = 0, ntP4 = 0;
  if (!isP3) {
    int vidx = tbase >> 3;
    mtP4 = vidx >> 3;
    ntP4 = (tbase & 7) * 8 + (vidx & 7);
  }
  const int ke_ = (lane >> 4) * 8;
  bfrag waoreg[4];
  if (!isP3) {
    const int browP4 = ntP4 * 16 + (lane & 15);
#pragma unroll
    for (int q = 0; q < 4; ++q)
      waoreg[q] = *(const bfrag*)(Wao + (long)browP4 * 2048 + 1024 + (w * 4 + q) * 32 + ke_);
  }

  const int mt_ = w & 3, kh_ = w >> 2;
  const int brow_ = lane & 15;

  for (int t = 0; t < 32; ++t) {
    const char* OFc = of_slot(wsb, t);
    const char* H0c = h0_slot(wsb, t);
    char*       H0n = h0_slot(wsb, t + 1);
    char*       H1n = h1_slot(wsb, t + 1);
    const char* H1c = h1_slot(wsb, t);

    // ---- P1: gates0 = emb(t)·Wie + OF(t)·Wif + h0(t)·Whh0 ----
    {
      f32x4 acc = {0.f, 0.f, 0.f, 0.f};
      const char* En = wsb + EBF_O + (long)t * 65536;
      if (kh_ == 0) gseg<2>(acc, En, 0, mt_, lane, W0, 2560, 0, brow_, ke_);
      else          gseg<2>(acc, En, 8, mt_, lane, W0, 2560, 8, brow_, ke_);
      if (t > 0) poll_chunks<16>(cntb(wsb, OFC_O, t), kh_ * 16);
      if (kh_ == 0) gseg<4>(acc, OFc, 0,  mt_, lane, W0, 2560, 16, brow_, ke_);
      else          gseg<4>(acc, OFc, 16, mt_, lane, W0, 2560, 32, brow_, ke_);
      if (t > 0) poll_chunks<16>(cntb(wsb, H0C_O, t), kh_ * 16);
      if (kh_ == 0) gseg<4>(acc, H0c, 0,  mt_, lane, W0, 2560, 48, brow_, ke_);
      else          gseg<4>(acc, H0c, 16, mt_, lane, W0, 2560, 64, brow_, ke_);
      scr_store(scr, mt_ * 2 + kh_, acc);
      __syncthreads();
      if (tid < 64) { pointwise64(bid, scr, p.b0, cR0, H0n); VMFLUSH(); }
      __syncthreads();
      if (tid == 0) cnt_add(cntb(wsb, H0C_O, t + 1) + (bid >> 3) * 16);
    }

    // ---- P2: gates1 = h0(t+1)·Wih1 + h1(t)·Whh1 ----
    {
      f32x4 acc = {0.f, 0.f, 0.f, 0.f};
      poll_chunks<16>(cntb(wsb, H0C_O, t + 1), kh_ * 16);
      if (kh_ == 0) gseg<4>(acc, H0n, 0,  mt_, lane, W1, 2048, 0,  brow_, ke_);
      else          gseg<4>(acc, H0n, 16, mt_, lane, W1, 2048, 16, brow_, ke_);
      if (t > 0) poll_chunks<16>(cntb(wsb, H1C_O, t), kh_ * 16);
      if (kh_ == 0) gseg<4>(acc, H1c, 0,  mt_, lane, W1, 2048, 32, brow_, ke_);
      else          gseg<4>(acc, H1c, 16, mt_, lane, W1, 2048, 48, brow_, ke_);
      scr_store(scr, mt_ * 2 + kh_, acc);
      __syncthreads();
      if (tid < 64) { pointwise64(bid, scr, p.b1, cR1, H1n); VMFLUSH(); }
      __syncthreads();
      if (tid == 0) cnt_add(cntb(wsb, H1C_O, t + 1) + (bid >> 3) * 16);
    }

    // ---- P3 (blocks 0..63) or P4 (blocks 64..255) ----
    if (isP3) {
      const int b = bid;
      poll_chunks<32>(cntb(wsb, H1C_O, t + 1), 0);
      float h1v[16];
      {
        int k0 = lane * 16;
        const u32* hp0 = (const u32*)(H1n + fragoff(b, k0));
        const u32* hp1 = (const u32*)(H1n + fragoff(b, k0 + 8));
        u32 uu[8] = {hp0[0], hp0[1], hp0[2], hp0[3], hp1[0], hp1[1], hp1[2], hp1[3]};
#pragma unroll
        for (int i = 0; i < 8; ++i) {
          h1v[2 * i]     = bf2f((u16)(uu[i] & 0xffff));
          h1v[2 * i + 1] = bf2f((u16)(uu[i] >> 16));
        }
      }
      const u16* cwb = CtxW + (long)b * 65536;
#pragma unroll
      for (int si = 0; si < 8; ++si) {
        int s = w * 8 + si;
        const u32* u = (const u32*)(cwb + (long)s * 1024 + lane * 16);
        float acc = 0.f;
#pragma unroll
        for (int i = 0; i < 8; ++i) {
          u32 x = u[i];
          acc += h1v[2 * i] * bf2f((u16)(x & 0xffff));
          acc += h1v[2 * i + 1] * bf2f((u16)(x >> 16));
        }
#pragma unroll
        for (int off = 32; off; off >>= 1) acc += __shfl_down(acc, off, 64);
        if (lane == 0) scr2[s] = acc;
      }
      __syncthreads();
      if (w == 0) {
        float v = scr2[lane];
        float mx = v;
#pragma unroll
        for (int off = 32; off; off >>= 1) mx = fmaxf(mx, __shfl_xor(mx, off, 64));
        float e = __expf(v - mx);
        float sm = e;
#pragma unroll
        for (int off = 32; off; off >>= 1) sm += __shfl_xor(sm, off, 64);
        float a = e / sm;
        ST4SC(wsb + AB_O + (long)t * 16384 + (u32)(b * 64 + lane) * 4, __builtin_bit_cast(u32, a));
        ST4SC((char*)(p.out + AS_OFF + (long)t * 4096 + b * 64 + lane), __builtin_bit_cast(u32, a));
        VMFLUSH();
        if (lane == 0)
          ST4SC(wsb + AFLAG_O + ((u32)t * 64 + b) * 4, 1u);
      }
      __syncthreads();
    } else {
      // in-loop copy-attention for step t-1 (blocks 192..255)
      if (bid >= 192 && t > 0) {
        poll_chunks<32>(cntb(wsb, OFC_O, t), 0);
        copyattn_step(bid - 192, t - 1, CtxWc, p.out, scr2, p.out);
        __syncthreads();
      }
      p4_tile(t, mtP4, ntP4, waoreg, H1n, wsb, CtxOT, scr, scr2, p.out);
      if (dual) {
        __syncthreads();
        p4_tile(t, mtP4 + 3, ntP4, waoreg, H1n, wsb, CtxOT, scr, scr2, p.out);
      }
    }
  }

  // ---- epilogue: final states (slot 32) ----
  if (w == 0) {
    poll_chunks<32>(cntb(wsb, H0C_O, 32), 0);
    poll_chunks<32>(cntb(wsb, H1C_O, 32), 0);
  }
  __syncthreads();
  if (tid < 64) {
#pragma unroll
    for (int u = 0; u < 4; ++u) {
      int j = bid * 4 + u;
      p.out[CT_OFF + (long)tid * 1024 + j]         = cR0[u];
      p.out[CT_OFF + 65536 + (long)tid * 1024 + j] = cR1[u];
    }
  }
  if (tid < 256) {
    int u = tid >> 6, m = tid & 63, j = bid * 4 + u;
    u16 a0 = *(const u16*)(h0_slot(wsb, 32) + fragoff(m, j));
    u16 a1 = *(const u16*)(h1_slot(wsb, 32) + fragoff(m, j));
    p.out[HT_OFF + (long)m * 1024 + j]         = bf2f(a0);
    p.out[HT_OFF + 65536 + (long)m * 1024 + j] = bf2f(a1);
  }

  // ---- final copy-attention step (tau = 31, blocks 192..255) ----
  if (bid >= 192) {
    poll_chunks<32>(cntb(wsb, OFC_O, 32), 0);
    __syncthreads();
    copyattn_step(bid - 192, 31, CtxWc, p.out, scr2, p.out);
  }
}

// ---------------- host ----------------
extern "C" void kernel_launch(void* const* d_in, const int* in_sizes, int n_in,
                              void* d_out, int out_size, void* d_ws, size_t ws_size,
                              hipStream_t stream) {
  KParams p;
  p.input       = (const int*)d_in[0];
  p.h0          = (const float*)d_in[1];
  p.c0          = (const float*)d_in[2];
  p.context     = (const float*)d_in[3];
  p.init_output = (const float*)d_in[4];
  p.embedding   = (const float*)d_in[5];
  p.W_ih0       = (const float*)d_in[6];
  p.W_hh0       = (const float*)d_in[7];
  p.b0          = (const float*)d_in[8];
  p.W_ih1       = (const float*)d_in[9];
  p.W_hh1       = (const float*)d_in[10];
  p.b1          = (const float*)d_in[11];
  p.attn_in     = (const float*)d_in[12];
  p.attn_out    = (const float*)d_in[13];
  p.copy_in     = (const float*)d_in[14];
  p.out         = (float*)d_out;
  p.ws          = (char*)d_ws;

  (void)hipFuncSetAttribute((const void*)decoder_kernel,
                            hipFuncAttributeMaxDynamicSharedMemorySize, 160256);
  // zero: a-buffer + aflags + h0/h1/OF chunk counters + setup barrier flags
  (void)hipMemsetAsync((char*)d_ws + AB_O, 0, 737280, stream);
  void* args[] = { &p };
  (void)hipLaunchCooperativeKernel((void*)decoder_kernel, dim3(256), dim3(512),
                                   args, 160256, stream);
}

// Round 13
// 1659.108 us; speedup vs baseline: 1.2152x; 1.2152x over previous
//
#include <hip/hip_runtime.h>

typedef unsigned short u16;
typedef unsigned int   u32;
typedef __attribute__((ext_vector_type(8))) __bf16 bfrag;   // 8 bf16 = 4 VGPR
typedef __attribute__((ext_vector_type(4))) float  f32x4;
typedef __attribute__((ext_vector_type(2))) u32    u32x2;
typedef __attribute__((ext_vector_type(4))) u32    u32x4;

#define DEVI static __device__ __forceinline__

// ---- ALL cross-visible global writes are sc0sc1 (write-through to LLC).
// ---- ALL reads are plain cached loads. Correctness: no global address is
// ---- written-after-cached-read within a launch (per-step slot rotation),
// ---- so no fences / cache invalidations are needed anywhere.
#define ST2SC(p, v)    asm volatile("global_store_short %0, %1, off sc0 sc1"   :: "v"(p), "v"(v) : "memory")
#define ST4SC(p, v)    asm volatile("global_store_dword %0, %1, off sc0 sc1"   :: "v"(p), "v"(v) : "memory")
#define ST8SC(p, v)    asm volatile("global_store_dwordx2 %0, %1, off sc0 sc1" :: "v"(p), "v"(v) : "memory")
#define ST16SC(p, v)   asm volatile("global_store_dwordx4 %0, %1, off sc0 sc1" :: "v"(p), "v"(v) : "memory")
#define VMFLUSH()      asm volatile("s_waitcnt vmcnt(0)" ::: "memory")

// ---------------- geometry ----------------
// T=32 B=64 S=64 E=512 H=1024 L=2 (4H=4096)
constexpr long OUT_OFF = 0;         // 32*64*1024
constexpr long HT_OFF  = 2097152;
constexpr long CT_OFF  = 2228224;
constexpr long AS_OFF  = 2359296;
constexpr long AC_OFF  = 2490368;

// ---------------- workspace layout (bytes) ----------------
// WAO dead after prologue (waoreg);  CTX dead after S1  ->  overlaid by slots.
constexpr long WAO_O   = 0;          // attn_out bf16 [1024][2048] (4MB)
constexpr long CTX_O   = 4194304;    // ctx (b,s,k) bf16 (8MB)
constexpr long OFR_O   = 0;          // OF slots 1..32  [0, 4MB)
constexpr long H0R_O   = 4194304;    // H0 slots 1..32
constexpr long H1R_O   = 8388608;    // H1 slots 1..32
constexpr long WAI_O   = 12582912;   // attn_in^T bf16 (2MB)
constexpr long WC_O    = 14680064;   // copy_in^T bf16 (2MB)
constexpr long CTXW_O  = 16777216;   // ctx @ Wai (8MB)
constexpr long CTXWC_O = 25165824;   // ctx @ Wc  (8MB)
constexpr long CTXOT_O = 33554432;   // (ctx @ Waoc)^T [b][j][s] (8MB)
constexpr long EBF_O   = 41943040;   // emb frag-major [t][...] (2MB)
constexpr long OF0_O   = 44040192;   // OF slot 0 (128KB)
constexpr long H00_O   = 44171264;   // H0 slot 0
constexpr long H10_O   = 44302336;   // H1 slot 0
constexpr long AB_O    = 44433408;   // a f32 [32 t][64 b][64 s] = 512KB
constexpr long AFLAG_O = 44957696;   // per-step a-ready flags [32 t][64 b] u32 = 8KB
constexpr long BAR_O   = 44965888;   // flags[256] + bcast word

// LDS layout (dynamic, 160256 B)
constexpr int W0LDS_O = 0;        // [16 rows][2560] bf16 swizzled = 81920
constexpr int W1LDS_O = 81920;    // [16 rows][2048] bf16 swizzled = 65536
constexpr int SCR_O   = 147456;   // 8 slots x 272 f32 = 8704
constexpr int SCR2_O  = 156160;   // 4096 B

struct KParams {
  const int* input; const float* h0; const float* c0; const float* context;
  const float* init_output; const float* embedding;
  const float* W_ih0; const float* W_hh0; const float* b0;
  const float* W_ih1; const float* W_hh1; const float* b1;
  const float* attn_in; const float* attn_out; const float* copy_in;
  float* out; char* ws;
};

// ---------------- small helpers ----------------
DEVI float bf2f(u16 u) { u32 x = ((u32)u) << 16; return __builtin_bit_cast(float, x); }
DEVI u16 f2bf(float f) {
  u32 x = __builtin_bit_cast(u32, f);
  u32 r = x + 0x7fffu + ((x >> 16) & 1u);   // RNE
  return (u16)(r >> 16);
}
DEVI void cvtc_sc(const float* s, char* d) {   // 4 f32 -> 4 bf16, sc store
  float4 v = *(const float4*)s;
  u32x2 u;
  u[0] = (u32)f2bf(v.x) | ((u32)f2bf(v.y) << 16);
  u[1] = (u32)f2bf(v.z) | ((u32)f2bf(v.w) << 16);
  ST8SC(d, u);
}
DEVI float sigm(float x)  { return 1.f / (1.f + __expf(-x)); }
DEVI float tanh_(float x) { return 1.f - 2.f / (__expf(2.f * x) + 1.f); }
DEVI f32x4 mfma16(bfrag a, bfrag b, f32x4 c) {
  return __builtin_amdgcn_mfma_f32_16x16x32_bf16(a, b, c, 0, 0, 0);
}
// frag-major byte offset for element (m,k) of a [64 m][K k] activation
DEVI u32 fragoff(int m, int k) {
  return (u32)((((k >> 5) * 4 + (m >> 4)) * 64 + ((k >> 3) & 3) * 16 + (m & 15)) * 16 + (k & 7) * 2);
}
// per-step slot addressing (slot 0 = initial state, slot t+1 = written at step t)
DEVI char* of_slot(char* w, int s) { return w + (s ? OFR_O + (long)(s - 1) * 131072 : OF0_O); }
DEVI char* h0_slot(char* w, int s) { return w + (s ? H0R_O + (long)(s - 1) * 131072 : H00_O); }
DEVI char* h1_slot(char* w, int s) { return w + (s ? H1R_O + (long)(s - 1) * 131072 : H10_O); }

// ---------------- barriers ----------------
DEVI void pollflags(u32* flags, u32 gen) {
  int t = threadIdx.x;   // < 64
  for (;;) {
    u32 a = __hip_atomic_load(&flags[t],       __ATOMIC_RELAXED, __HIP_MEMORY_SCOPE_AGENT);
    u32 b = __hip_atomic_load(&flags[64 + t],  __ATOMIC_RELAXED, __HIP_MEMORY_SCOPE_AGENT);
    u32 c = __hip_atomic_load(&flags[128 + t], __ATOMIC_RELAXED, __HIP_MEMORY_SCOPE_AGENT);
    u32 d = __hip_atomic_load(&flags[192 + t], __ATOMIC_RELAXED, __HIP_MEMORY_SCOPE_AGENT);
    if (__all((a >= gen) && (b >= gen) && (c >= gen) && (d >= gen))) break;
  }
}
DEVI void barr_arrive(u32* flags, u32 gen) {
  VMFLUSH();               // drain sc stores to LLC before signaling
  __syncthreads();
  if (threadIdx.x == 0)
    __hip_atomic_store(&flags[blockIdx.x], gen, __ATOMIC_RELAXED, __HIP_MEMORY_SCOPE_AGENT);
}
DEVI void barr_wait(u32* flags, u32 gen) {
  u32* bc = flags + 320;   // broadcast word, own cache line
  if (blockIdx.x == 128) {
    if (threadIdx.x < 64) pollflags(flags, gen);
    __syncthreads();
    if (threadIdx.x == 0)
      __hip_atomic_store(bc, gen, __ATOMIC_RELAXED, __HIP_MEMORY_SCOPE_AGENT);
  } else {
    if (threadIdx.x == 0) {
      while (__hip_atomic_load(bc, __ATOMIC_RELAXED, __HIP_MEMORY_SCOPE_AGENT) < gen) {}
    }
  }
  __syncthreads();
  asm volatile("" ::: "memory");
}
// fenced barrier (setup only)
DEVI void gsync_fence(u32* flags, u32 gen) {
  __syncthreads();
  if (threadIdx.x == 0) {
    __builtin_amdgcn_fence(__ATOMIC_RELEASE, "agent");
    __hip_atomic_store(&flags[blockIdx.x], gen, __ATOMIC_RELAXED, __HIP_MEMORY_SCOPE_AGENT);
  }
  if (threadIdx.x < 64) pollflags(flags, gen);
  if (threadIdx.x == 0) __builtin_amdgcn_fence(__ATOMIC_ACQUIRE, "agent");
  __syncthreads();
}

// ---------------- gate-GEMM segment: cached loads, compiler-pipelined ----------------
template<int N4>
DEVI void gseg(f32x4& acc, const char* Af, int kkA0, int mt, int lane,
               const char* W, int wRowK, int kkW0, int brow, int ke) {
  const u32 sw = (u32)((brow & 7) << 4);
#pragma unroll
  for (int g = 0; g < N4; ++g) {
#pragma unroll
    for (int q = 0; q < 4; ++q) {
      const char* pa = Af + ((((kkA0 + g * 4 + q) * 4 + mt) * 64 + lane) << 4);
      bfrag av = *(const bfrag*)pa;
      int kkW = kkW0 + g * 4 + q;
      u32 off = ((u32)(brow * wRowK + kkW * 32 + ke) * 2) ^ sw;
      acc = mfma16(av, *(const bfrag*)(W + off), acc);
    }
  }
}

DEVI void scr_store(float* scr, int slot, f32x4 acc) {
  const int lane = threadIdx.x & 63;
#pragma unroll
  for (int r = 0; r < 4; ++r)
    scr[slot * 272 + ((lane >> 4) * 4 + r) * 17 + (lane & 15)] = acc[r];
}

// LSTM pointwise: threads 0..63; c-state in registers; one 8B sc h-store
DEVI void pointwise64(int bid, const float* scr, const float* bias, float (&cst)[4], char* hfrag) {
  const int m = threadIdx.x;            // < 64
  const int mt = m >> 4, ml = m & 15;
  u32 hp0 = 0, hp1 = 0;
#pragma unroll
  for (int u = 0; u < 4; ++u) {
    const int j = bid * 4 + u;
    float g0 = scr[(mt*2)*272 + ml*17 + u]      + scr[(mt*2+1)*272 + ml*17 + u]      + bias[j];
    float g1 = scr[(mt*2)*272 + ml*17 + 4 + u]  + scr[(mt*2+1)*272 + ml*17 + 4 + u]  + bias[1024 + j];
    float g2 = scr[(mt*2)*272 + ml*17 + 8 + u]  + scr[(mt*2+1)*272 + ml*17 + 8 + u]  + bias[2048 + j];
    float g3 = scr[(mt*2)*272 + ml*17 + 12 + u] + scr[(mt*2+1)*272 + ml*17 + 12 + u] + bias[3072 + j];
    float cn = sigm(g1) * cst[u] + sigm(g0) * tanh_(g2);
    cst[u] = cn;
    u32 hb = (u32)f2bf(sigm(g3) * tanh_(cn));
    if (u == 0) hp0 = hb; else if (u == 1) hp0 |= hb << 16;
    else if (u == 2) hp1 = hb; else hp1 |= hb << 16;
  }
  u32x2 v; v[0] = hp0; v[1] = hp1;
  ST8SC(hfrag + fragoff(m, bid * 4), v);
}

// copy-attention for one (batch, step): scores from global CtxWc, softmax, AC out
DEVI void copyattn_step(int b, int tau, const u16* CtxWc, const float* outp,
                        float* xch, float* dout) {
  const int tid = threadIdx.x, lane = tid & 63, w = tid >> 6;
  float ov[16];
  {
    const float4* op = (const float4*)(outp + (long)tau * 65536 + b * 1024 + lane * 16);
#pragma unroll
    for (int i = 0; i < 4; ++i) {
      float4 v = op[i];
      ov[4 * i] = v.x; ov[4 * i + 1] = v.y; ov[4 * i + 2] = v.z; ov[4 * i + 3] = v.w;
    }
  }
  const u16* cwb = CtxWc + (long)b * 65536;
#pragma unroll
  for (int si = 0; si < 8; ++si) {
    int s = w * 8 + si;
    const u32* u = (const u32*)(cwb + (long)s * 1024 + lane * 16);
    float acc = 0.f;
#pragma unroll
    for (int i = 0; i < 8; ++i) {
      u32 x = u[i];
      acc += ov[2 * i] * bf2f((u16)(x & 0xffff));
      acc += ov[2 * i + 1] * bf2f((u16)(x >> 16));
    }
#pragma unroll
    for (int off = 32; off; off >>= 1) acc += __shfl_down(acc, off, 64);
    if (lane == 0) xch[s] = acc;
  }
  __syncthreads();
  if (w == 0) {
    float v = xch[lane];
    float mx = v;
#pragma unroll
    for (int off = 32; off; off >>= 1) mx = fmaxf(mx, __shfl_xor(mx, off, 64));
    float e = __expf(v - mx);
    float sm = e;
#pragma unroll
    for (int off = 32; off; off >>= 1) sm += __shfl_xor(sm, off, 64);
    dout[AC_OFF + (long)tau * 4096 + b * 64 + lane] = e / sm;
  }
}

// setup GEMMs (sc stores)
DEVI void ctxw_gemm(int mt, const u16* Ctx, const u16* Wm, u16* dst) {
  const int tid = threadIdx.x, lane = tid & 63, w = tid >> 6;
  const int arow = mt * 16 + (lane & 15);
  const int ke = (lane >> 4) * 8;
#pragma unroll
  for (int i = 0; i < 8; ++i) {
    int nt = w * 8 + i;
    const u16* A = Ctx + (long)arow * 1024 + ke;
    const u16* B = Wm + (long)(nt * 16 + (lane & 15)) * 1024 + ke;
    f32x4 acc = {0.f, 0.f, 0.f, 0.f};
    for (int kk = 0; kk < 1024; kk += 32)
      acc = mfma16(*(const bfrag*)(A + kk), *(const bfrag*)(B + kk), acc);
#pragma unroll
    for (int r = 0; r < 4; ++r)
      ST2SC((char*)(dst + (long)(mt * 16 + (lane >> 4) * 4 + r) * 1024 + nt * 16 + (lane & 15)),
            (u32)f2bf(acc[r]));
  }
}
DEVI void ctxo_gemm(int bid, const u16* Ctx, const u16* Wao, u16* dst) {
  const int tid = threadIdx.x, lane = tid & 63, w = tid >> 6;
  const int arow = bid * 16 + (lane & 15);
  const int ke = (lane >> 4) * 8;
  const int b = bid >> 2, s0 = (bid & 3) * 16 + (lane >> 4) * 4;
#pragma unroll
  for (int i = 0; i < 8; ++i) {
    int nt = w * 8 + i;
    int j = nt * 16 + (lane & 15);
    const u16* A = Ctx + (long)arow * 1024 + ke;
    const u16* B = Wao + (long)j * 2048 + ke;
    f32x4 acc = {0.f, 0.f, 0.f, 0.f};
    for (int kk = 0; kk < 1024; kk += 32)
      acc = mfma16(*(const bfrag*)(A + kk), *(const bfrag*)(B + kk), acc);
    u32x2 q;
    q[0] = (u32)f2bf(acc[0]) | ((u32)f2bf(acc[1]) << 16);
    q[1] = (u32)f2bf(acc[2]) | ((u32)f2bf(acc[3]) << 16);
    ST8SC((char*)(dst + ((long)(b * 1024 + j) * 64 + s0)), q);
  }
}

// P4 tile (h1 ready via barrier): P4h + aflag-wait + P4c -> out(t), OF(t+1)
DEVI void p4_tile(int t, int mt, int nt, const bfrag (&waoreg)[4],
                  const char* H1n, char* wsb, const u16* CtxOT,
                  float* scr, float* scr2, float* outp) {
  const int tid = threadIdx.x, lane = tid & 63, w = tid >> 6;
  // P4h: h1-half of out-projection, 8-way K-split
  {
    bfrag h0_ = *(const bfrag*)(H1n + ((((w * 4 + 0) * 4 + mt) * 64 + lane) << 4));
    bfrag h1_ = *(const bfrag*)(H1n + ((((w * 4 + 1) * 4 + mt) * 64 + lane) << 4));
    bfrag h2_ = *(const bfrag*)(H1n + ((((w * 4 + 2) * 4 + mt) * 64 + lane) << 4));
    bfrag h3_ = *(const bfrag*)(H1n + ((((w * 4 + 3) * 4 + mt) * 64 + lane) << 4));
    f32x4 a4 = {0.f, 0.f, 0.f, 0.f};
    a4 = mfma16(h0_, waoreg[0], a4);
    a4 = mfma16(h1_, waoreg[1], a4);
    a4 = mfma16(h2_, waoreg[2], a4);
    a4 = mfma16(h3_, waoreg[3], a4);
    scr_store(scr, w, a4);
  }
  // CtxOT prefetch -> regs (off the a-critical path)
  const int pair = tid >> 1, half = tid & 1;
  const int m_l = pair >> 4, j_l = pair & 15;
  const int b = mt * 16 + m_l, j = nt * 16 + j_l;
  u32 cpr[16];
  {
    const u32* cp = (const u32*)(CtxOT + ((long)(b * 1024 + j) * 64 + half * 32));
#pragma unroll
    for (int i = 0; i < 16; ++i) cpr[i] = cp[i];
  }
  // wait for a(t) of this tile's batches
  char* ABt = wsb + AB_O + (long)t * 16384;
  if (tid < 16) {
    const u32* fp = (const u32*)(wsb + AFLAG_O + ((u32)t * 64 + mt * 16 + tid) * 4);
    while (__hip_atomic_load(fp, __ATOMIC_RELAXED, __HIP_MEMORY_SCOPE_AGENT) == 0) {}
  }
  __syncthreads();
  {
    int b0i = tid >> 6, s0i = tid & 63;
    int b1i = (tid + 512) >> 6;
    scr2[tid]       = *(const float*)(ABt + (u32)(((mt * 16 + b0i) * 64 + s0i)) * 4);
    scr2[tid + 512] = *(const float*)(ABt + (u32)(((mt * 16 + b1i) * 64 + s0i)) * 4);
  }
  __syncthreads();
  const float* al = scr2 + m_l * 64 + half * 32;
  float acc = 0.f;
#pragma unroll
  for (int i = 0; i < 16; ++i) {
    u32 x = cpr[i];
    acc += al[2 * i] * bf2f((u16)(x & 0xffff));
    acc += al[2 * i + 1] * bf2f((u16)(x >> 16));
  }
  float v = acc + __shfl_xor(acc, 1, 64);
  if (half == 0) {
    float h1p = 0.f;
#pragma unroll
    for (int q = 0; q < 8; ++q) h1p += scr[q * 272 + m_l * 17 + j_l];
    v = tanh_(v + h1p);
    ST4SC((char*)(outp + (long)t * 65536 + b * 1024 + j), __builtin_bit_cast(u32, v));
    u32 hv = (u32)f2bf(v);
    ST2SC(of_slot(wsb, t + 1) + fragoff(b, j), hv);
  }
}

// ---------------- the kernel ----------------
__global__ __launch_bounds__(512, 1) void decoder_kernel(KParams p) {
  extern __shared__ char smem[];
  char*  W0   = smem + W0LDS_O;
  char*  W1   = smem + W1LDS_O;
  float* scr  = (float*)(smem + SCR_O);
  float* scr2 = (float*)(smem + SCR2_O);

  char* wsb = p.ws;
  u16* Wao   = (u16*)(wsb + WAO_O);
  u16* Wai   = (u16*)(wsb + WAI_O);
  u16* Wc    = (u16*)(wsb + WC_O);
  u16* Ctx   = (u16*)(wsb + CTX_O);
  u16* CtxW  = (u16*)(wsb + CTXW_O);
  u16* CtxWc = (u16*)(wsb + CTXWC_O);
  u16* CtxOT = (u16*)(wsb + CTXOT_O);
  u32* bar   = (u32*)(wsb + BAR_O);

  const int bid = blockIdx.x, tid = threadIdx.x;
  const int lane = tid & 63, w = tid >> 6;
  const long gtid = (long)bid * 512 + tid, NT = 256l * 512;
  u32 gen = 1;

  // ---- S0-pre: LDS-tiled transposes of attn_in / copy_in (sc out) ----
  {
    float* tile = (float*)smem;
    for (int pass = 0; pass < 2; ++pass) {
      const float* src = pass ? p.copy_in : p.attn_in;
      u16* dst = pass ? Wc : Wai;
      int tr = bid >> 4, tc = bid & 15;
      {
        int r = tid >> 3, c = (tid & 7) * 8;
        const float4* s4 = (const float4*)(src + (long)(tr * 64 + r) * 1024 + tc * 64 + c);
        float4 a = s4[0], b = s4[1];
        float* tp = tile + r * 69 + c;
        tp[0] = a.x; tp[1] = a.y; tp[2] = a.z; tp[3] = a.w;
        tp[4] = b.x; tp[5] = b.y; tp[6] = b.z; tp[7] = b.w;
      }
      __syncthreads();
      {
        int r2 = tid >> 3, c2 = (tid & 7) * 8;
        u32x4 q;
#pragma unroll
        for (int i = 0; i < 4; ++i) {
          float lo = tile[(c2 + 2 * i) * 69 + r2];
          float hi = tile[(c2 + 2 * i + 1) * 69 + r2];
          q[i] = (u32)f2bf(lo) | ((u32)f2bf(hi) << 16);
        }
        ST16SC((char*)(dst + (long)(tc * 64 + r2) * 1024 + tr * 64 + c2), q);
      }
      __syncthreads();
    }
  }

  // ---- S0a: per-block weight slices -> LDS (stationary all 32 steps) ----
  for (int i = tid; i < 5120; i += 512) {
    int row = i / 320, k = (i % 320) * 8;
    int R = (row >> 2) * 1024 + bid * 4 + (row & 3);
    const float* src = (k < 1536) ? (p.W_ih0 + (long)R * 1536 + k)
                                  : (p.W_hh0 + (long)R * 1024 + (k - 1536));
    float4 a = *(const float4*)src, b = *(const float4*)(src + 4);
    uint4 q;
    q.x = (u32)f2bf(a.x) | ((u32)f2bf(a.y) << 16);
    q.y = (u32)f2bf(a.z) | ((u32)f2bf(a.w) << 16);
    q.z = (u32)f2bf(b.x) | ((u32)f2bf(b.y) << 16);
    q.w = (u32)f2bf(b.z) | ((u32)f2bf(b.w) << 16);
    u32 off = ((u32)(row * 2560 + k) * 2) ^ ((u32)((row & 7) << 4));
    *(uint4*)(W0 + off) = q;
  }
  for (int i = tid; i < 4096; i += 512) {
    int row = i / 256, k = (i % 256) * 8;
    int R = (row >> 2) * 1024 + bid * 4 + (row & 3);
    const float* src = (k < 1024) ? (p.W_ih1 + (long)R * 1024 + k)
                                  : (p.W_hh1 + (long)R * 1024 + (k - 1024));
    float4 a = *(const float4*)src, b = *(const float4*)(src + 4);
    uint4 q;
    q.x = (u32)f2bf(a.x) | ((u32)f2bf(a.y) << 16);
    q.y = (u32)f2bf(a.z) | ((u32)f2bf(a.w) << 16);
    q.z = (u32)f2bf(b.x) | ((u32)f2bf(b.y) << 16);
    q.w = (u32)f2bf(b.z) | ((u32)f2bf(b.w) << 16);
    u32 off = ((u32)(row * 2048 + k) * 2) ^ ((u32)((row & 7) << 4));
    *(uint4*)(W1 + off) = q;
  }

  // ---- S0b: global conversions (all sc stores) ----
  for (long i = gtid; i < 524288; i += NT) cvtc_sc(p.attn_out + i * 4, (char*)(Wao + i * 4));
  for (long i = gtid; i < 1048576; i += NT) {
    long b = i >> 14, s = (i >> 8) & 63, kq = i & 255;
    cvtc_sc(p.context + ((s * 64 + b) * 1024 + kq * 4), (char*)(Ctx + i * 4));
  }
  for (long i = gtid; i < 262144; i += NT) {     // emb gather -> frag-major
    long row = i >> 7; long t = row >> 6, b = row & 63;
    long k0 = (i & 127) * 4;
    long tok = p.input[row];
    cvtc_sc(p.embedding + tok * 512 + k0, wsb + EBF_O + t * 65536 + fragoff((int)b, (int)k0));
  }
  for (long i = gtid; i < 16384; i += NT) {      // init_output -> OF slot 0
    long b = i >> 8, k0 = (i & 255) * 4;
    cvtc_sc(p.init_output + i * 4, of_slot(wsb, 0) + fragoff((int)b, (int)k0));
  }
  for (long i = gtid; i < 32768; i += NT) {      // h0 -> h slots 0
    long l = i >> 14, rem = i & 16383, b = rem >> 8, k0 = (rem & 255) * 4;
    cvtc_sc(p.h0 + i * 4, (l ? h1_slot(wsb, 0) : h0_slot(wsb, 0)) + fragoff((int)b, (int)k0));
  }

  // ---- c-state -> registers (threads 0..63; thread m owns (m, j=bid*4+u)) ----
  float cR0[4] = {0.f, 0.f, 0.f, 0.f}, cR1[4] = {0.f, 0.f, 0.f, 0.f};
  if (tid < 64) {
#pragma unroll
    for (int u = 0; u < 4; ++u) {
      cR0[u] = p.c0[(long)tid * 1024 + bid * 4 + u];
      cR1[u] = p.c0[65536 + (long)tid * 1024 + bid * 4 + u];
    }
  }

  gsync_fence(bar, gen); ++gen;

  // ---- S1: attention tables ----
  ctxw_gemm(bid, Ctx, Wai, CtxW);
  ctxw_gemm(bid, Ctx, Wc, CtxWc);
  ctxo_gemm(bid, Ctx, Wao, CtxOT);
  gsync_fence(bar, gen); ++gen;

  // ---- role assignment ----
  // blocks 0..63: P3 only.  blocks 64..255: own tile (mt = idx>>3 in 1..3,
  // nt = xcd*8 + (idx&7)); blocks 64..127 additionally take the mt=0 tile
  // with the SAME nt (block 64+k shares nt with block k) -> shared waoreg.
  const bool isP3 = bid < 64;
  const bool dual = (bid >= 64) && (bid < 128);
  int mtP4 = 0, ntP4 = 0;
  if (!isP3) {
    const int xcd = bid & 7, idx = bid >> 3;
    ntP4 = xcd * 8 + (idx & 7);
    mtP4 = idx >> 3;   // 1..3
  }
  const int ke_ = (lane >> 4) * 8;
  bfrag waoreg[4];
  if (!isP3) {
    const int browP4 = ntP4 * 16 + (lane & 15);
#pragma unroll
    for (int q = 0; q < 4; ++q)
      waoreg[q] = *(const bfrag*)(Wao + (long)browP4 * 2048 + 1024 + (w * 4 + q) * 32 + ke_);
  }

  const int mt_ = w & 3, kh_ = w >> 2;
  const int brow_ = lane & 15;

  // ---- pre-loop P1(0) lookahead: emb(0) + h0 slot 0 ----
  f32x4 accP1 = {0.f, 0.f, 0.f, 0.f}, accP2;
  {
    const char* E0  = wsb + EBF_O;
    const char* H0p = h0_slot(wsb, 0);
    if (kh_ == 0) {
      gseg<2>(accP1, E0,  0,  mt_, lane, W0, 2560, 0,  brow_, ke_);
      gseg<4>(accP1, H0p, 0,  mt_, lane, W0, 2560, 48, brow_, ke_);
    } else {
      gseg<2>(accP1, E0,  8,  mt_, lane, W0, 2560, 8,  brow_, ke_);
      gseg<4>(accP1, H0p, 16, mt_, lane, W0, 2560, 64, brow_, ke_);
    }
  }

  for (int t = 0; t < 32; ++t) {
    const char* OFc   = of_slot(wsb, t);
    char*       Hb0cF = h0_slot(wsb, t + 1);
    char*       Hb1cF = h1_slot(wsb, t + 1);
    const char* Hb1pF = h1_slot(wsb, t);
    char*       ABt   = wsb + AB_O + (long)t * 16384;

    // ---- P1 remainder: out-feed segment ----
    {
      f32x4 acc = accP1;
      if (kh_ == 0) gseg<4>(acc, OFc, 0,  mt_, lane, W0, 2560, 16, brow_, ke_);
      else          gseg<4>(acc, OFc, 16, mt_, lane, W0, 2560, 32, brow_, ke_);
      scr_store(scr, mt_ * 2 + kh_, acc);
      __syncthreads();
      if (tid < 64) pointwise64(bid, scr, p.b0, cR0, Hb0cF);
    }
    barr_arrive(bar, gen);
    // P2 lookahead: h1prev segment
    accP2 = f32x4{0.f, 0.f, 0.f, 0.f};
    if (kh_ == 0) gseg<4>(accP2, Hb1pF, 0,  mt_, lane, W1, 2048, 32, brow_, ke_);
    else          gseg<4>(accP2, Hb1pF, 16, mt_, lane, W1, 2048, 48, brow_, ke_);
    barr_wait(bar, gen); ++gen;

    // ---- P2 remainder: h0new segment ----
    {
      f32x4 acc = accP2;
      if (kh_ == 0) gseg<4>(acc, Hb0cF, 0,  mt_, lane, W1, 2048, 0,  brow_, ke_);
      else          gseg<4>(acc, Hb0cF, 16, mt_, lane, W1, 2048, 16, brow_, ke_);
      scr_store(scr, mt_ * 2 + kh_, acc);
      __syncthreads();
      if (tid < 64) pointwise64(bid, scr, p.b1, cR1, Hb1cF);
    }
    barr_arrive(bar, gen);
    // P1(t+1) lookahead part A: emb(t+1) + first half of h0(t+1)
    accP1 = f32x4{0.f, 0.f, 0.f, 0.f};
    {
      const char* En = wsb + EBF_O + (long)((t + 1) & 31) * 65536;
      if (kh_ == 0) {
        gseg<2>(accP1, En,    0,  mt_, lane, W0, 2560, 0,  brow_, ke_);
        gseg<2>(accP1, Hb0cF, 0,  mt_, lane, W0, 2560, 48, brow_, ke_);
      } else {
        gseg<2>(accP1, En,    8,  mt_, lane, W0, 2560, 8,  brow_, ke_);
        gseg<2>(accP1, Hb0cF, 16, mt_, lane, W0, 2560, 64, brow_, ke_);
      }
    }
    barr_wait(bar, gen); ++gen;

    // ---- window 3: P3 (blocks 0..63) | P4 tiles (blocks 64..255) ----
    if (isP3) {
      const int b = bid;
      float h1v[16];
      {
        int k0 = lane * 16;
        const u32* hp0 = (const u32*)(Hb1cF + fragoff(b, k0));
        const u32* hp1 = (const u32*)(Hb1cF + fragoff(b, k0 + 8));
        u32 uu[8] = {hp0[0], hp0[1], hp0[2], hp0[3], hp1[0], hp1[1], hp1[2], hp1[3]};
#pragma unroll
        for (int i = 0; i < 8; ++i) {
          h1v[2 * i]     = bf2f((u16)(uu[i] & 0xffff));
          h1v[2 * i + 1] = bf2f((u16)(uu[i] >> 16));
        }
      }
      const u16* cwb = CtxW + (long)b * 65536;
#pragma unroll
      for (int si = 0; si < 8; ++si) {
        int s = w * 8 + si;
        const u32* u = (const u32*)(cwb + (long)s * 1024 + lane * 16);
        float acc = 0.f;
#pragma unroll
        for (int i = 0; i < 8; ++i) {
          u32 x = u[i];
          acc += h1v[2 * i] * bf2f((u16)(x & 0xffff));
          acc += h1v[2 * i + 1] * bf2f((u16)(x >> 16));
        }
#pragma unroll
        for (int off = 32; off; off >>= 1) acc += __shfl_down(acc, off, 64);
        if (lane == 0) scr2[s] = acc;
      }
      __syncthreads();
      if (w == 0) {
        float v = scr2[lane];
        float mx = v;
#pragma unroll
        for (int off = 32; off; off >>= 1) mx = fmaxf(mx, __shfl_xor(mx, off, 64));
        float e = __expf(v - mx);
        float sm = e;
#pragma unroll
        for (int off = 32; off; off >>= 1) sm += __shfl_xor(sm, off, 64);
        float a = e / sm;
        ST4SC(ABt + (u32)(b * 64 + lane) * 4, __builtin_bit_cast(u32, a));
        ST4SC((char*)(p.out + AS_OFF + (long)t * 4096 + b * 64 + lane), __builtin_bit_cast(u32, a));
        VMFLUSH();   // a-values at LLC before ready flag
        if (lane == 0)
          ST4SC(wsb + AFLAG_O + ((u32)t * 64 + b) * 4, 1u);
      }
      __syncthreads();
    } else {
      // in-loop copy-attention for step t-1 (blocks 192..255)
      if (bid >= 192 && t > 0) {
        copyattn_step(bid - 192, t - 1, CtxWc, p.out, scr2, p.out);
        __syncthreads();
      }
      p4_tile(t, mtP4, ntP4, waoreg, Hb1cF, wsb, CtxOT, scr, scr2, p.out);
      if (dual) {
        __syncthreads();
        p4_tile(t, 0, ntP4, waoreg, Hb1cF, wsb, CtxOT, scr, scr2, p.out);
      }
    }
    barr_arrive(bar, gen);
    // P1(t+1) lookahead part B: second half of h0(t+1)
    if (kh_ == 0) gseg<2>(accP1, Hb0cF, 8,  mt_, lane, W0, 2560, 56, brow_, ke_);
    else          gseg<2>(accP1, Hb0cF, 24, mt_, lane, W0, 2560, 72, brow_, ke_);
    barr_wait(bar, gen); ++gen;
  }

  // ---- epilogue: final states (slot 32; h from frag, c from registers) ----
  if (tid < 64) {
#pragma unroll
    for (int u = 0; u < 4; ++u) {
      int j = bid * 4 + u;
      p.out[CT_OFF + (long)tid * 1024 + j]         = cR0[u];
      p.out[CT_OFF + 65536 + (long)tid * 1024 + j] = cR1[u];
    }
  }
  if (tid < 256) {
    int u = tid >> 6, m = tid & 63, j = bid * 4 + u;
    u16 a0 = *(const u16*)(h0_slot(wsb, 32) + fragoff(m, j));
    u16 a1 = *(const u16*)(h1_slot(wsb, 32) + fragoff(m, j));
    p.out[HT_OFF + (long)m * 1024 + j]         = bf2f(a0);
    p.out[HT_OFF + 65536 + (long)m * 1024 + j] = bf2f(a1);
  }

  // ---- final copy-attention step (tau = 31, blocks 192..255) ----
  if (bid >= 192) {
    __syncthreads();
    copyattn_step(bid - 192, 31, CtxWc, p.out, scr2, p.out);
  }
}

// ---------------- host ----------------
extern "C" void kernel_launch(void* const* d_in, const int* in_sizes, int n_in,
                              void* d_out, int out_size, void* d_ws, size_t ws_size,
                              hipStream_t stream) {
  KParams p;
  p.input       = (const int*)d_in[0];
  p.h0          = (const float*)d_in[1];
  p.c0          = (const float*)d_in[2];
  p.context     = (const float*)d_in[3];
  p.init_output = (const float*)d_in[4];
  p.embedding   = (const float*)d_in[5];
  p.W_ih0       = (const float*)d_in[6];
  p.W_hh0       = (const float*)d_in[7];
  p.b0          = (const float*)d_in[8];
  p.W_ih1       = (const float*)d_in[9];
  p.W_hh1       = (const float*)d_in[10];
  p.b1          = (const float*)d_in[11];
  p.attn_in     = (const float*)d_in[12];
  p.attn_out    = (const float*)d_in[13];
  p.copy_in     = (const float*)d_in[14];
  p.out         = (float*)d_out;
  p.ws          = (char*)d_ws;

  (void)hipFuncSetAttribute((const void*)decoder_kernel,
                            hipFuncAttributeMaxDynamicSharedMemorySize, 160256);
  // zero: a-buffer (512KB) + a-ready flags (8KB) + barrier flags/bcast (2KB)
  (void)hipMemsetAsync((char*)d_ws + AB_O, 0, 534528, stream);
  void* args[] = { &p };
  (void)hipLaunchCooperativeKernel((void*)decoder_kernel, dim3(256), dim3(512),
                                   args, 160256, stream);
}

// Round 14
// 1529.376 us; speedup vs baseline: 1.3183x; 1.0848x over previous
//
#include <hip/hip_runtime.h>

typedef unsigned short u16;
typedef unsigned int   u32;
typedef __attribute__((ext_vector_type(8))) __bf16 bfrag;   // 8 bf16 = 4 VGPR
typedef __attribute__((ext_vector_type(4))) float  f32x4;
typedef __attribute__((ext_vector_type(2))) u32    u32x2;
typedef __attribute__((ext_vector_type(4))) u32    u32x4;

#define DEVI static __device__ __forceinline__

// ---- ALL cross-visible global writes are sc0sc1 (write-through to LLC).
// ---- ALL reads are plain cached loads. Correctness: no global address is
// ---- written-after-cached-read within a launch (per-step slot rotation),
// ---- so no fences / cache invalidations are needed anywhere.
#define ST2SC(p, v)    asm volatile("global_store_short %0, %1, off sc0 sc1"   :: "v"(p), "v"(v) : "memory")
#define ST4SC(p, v)    asm volatile("global_store_dword %0, %1, off sc0 sc1"   :: "v"(p), "v"(v) : "memory")
#define ST8SC(p, v)    asm volatile("global_store_dwordx2 %0, %1, off sc0 sc1" :: "v"(p), "v"(v) : "memory")
#define ST16SC(p, v)   asm volatile("global_store_dwordx4 %0, %1, off sc0 sc1" :: "v"(p), "v"(v) : "memory")
#define VMFLUSH()      asm volatile("s_waitcnt vmcnt(0)" ::: "memory")

// ---------------- geometry ----------------
// T=32 B=64 S=64 E=512 H=1024 L=2 (4H=4096)
constexpr long OUT_OFF = 0;         // 32*64*1024
constexpr long HT_OFF  = 2097152;
constexpr long CT_OFF  = 2228224;
constexpr long AS_OFF  = 2359296;
constexpr long AC_OFF  = 2490368;

// ---------------- workspace layout (bytes) ----------------
// WAO dead after prologue (waoreg);  CTX dead after S1  ->  overlaid by slots.
constexpr long WAO_O   = 0;          // attn_out bf16 [1024][2048] (4MB)
constexpr long CTX_O   = 4194304;    // ctx (b,s,k) bf16 (8MB)
constexpr long OFR_O   = 0;          // OF slots 1..32  [0, 4MB)
constexpr long H0R_O   = 4194304;    // H0 slots 1..32
constexpr long H1R_O   = 8388608;    // H1 slots 1..32
constexpr long WAI_O   = 12582912;   // attn_in^T bf16 (2MB)
constexpr long WC_O    = 14680064;   // copy_in^T bf16 (2MB)
constexpr long CTXW_O  = 16777216;   // ctx @ Wai (8MB)
constexpr long CTXWC_O = 25165824;   // ctx @ Wc  (8MB)
constexpr long CTXOT_O = 33554432;   // (ctx @ Waoc)^T [b][j][s] (8MB)
constexpr long EBF_O   = 41943040;   // emb frag-major [t][...] (2MB)
constexpr long OF0_O   = 44040192;   // OF slot 0 (128KB)
constexpr long H00_O   = 44171264;   // H0 slot 0
constexpr long H10_O   = 44302336;   // H1 slot 0
constexpr long AB_O    = 44433408;   // a f32 [32 t][64 b][64 s] = 512KB
constexpr long AFLAG_O = 44957696;   // per-step a-ready flags [32 t][64 b] u32 = 8KB
constexpr long BAR_O   = 44965888;   // flags[256] + bcast word

// LDS layout (dynamic, 160256 B)
constexpr int W0LDS_O = 0;        // [16 rows][2560] bf16 swizzled = 81920
constexpr int W1LDS_O = 81920;    // [16 rows][2048] bf16 swizzled = 65536
constexpr int SCR_O   = 147456;   // 8 slots x 272 f32 = 8704
constexpr int SCR2_O  = 156160;   // 4096 B

struct KParams {
  const int* input; const float* h0; const float* c0; const float* context;
  const float* init_output; const float* embedding;
  const float* W_ih0; const float* W_hh0; const float* b0;
  const float* W_ih1; const float* W_hh1; const float* b1;
  const float* attn_in; const float* attn_out; const float* copy_in;
  float* out; char* ws;
};

// ---------------- small helpers ----------------
DEVI float bf2f(u16 u) { u32 x = ((u32)u) << 16; return __builtin_bit_cast(float, x); }
DEVI u16 f2bf(float f) {
  u32 x = __builtin_bit_cast(u32, f);
  u32 r = x + 0x7fffu + ((x >> 16) & 1u);   // RNE
  return (u16)(r >> 16);
}
DEVI void cvtc_sc(const float* s, char* d) {   // 4 f32 -> 4 bf16, sc store
  float4 v = *(const float4*)s;
  u32x2 u;
  u[0] = (u32)f2bf(v.x) | ((u32)f2bf(v.y) << 16);
  u[1] = (u32)f2bf(v.z) | ((u32)f2bf(v.w) << 16);
  ST8SC(d, u);
}
DEVI float sigm(float x)  { return 1.f / (1.f + __expf(-x)); }
DEVI float tanh_(float x) { return 1.f - 2.f / (__expf(2.f * x) + 1.f); }
DEVI f32x4 mfma16(bfrag a, bfrag b, f32x4 c) {
  return __builtin_amdgcn_mfma_f32_16x16x32_bf16(a, b, c, 0, 0, 0);
}
// frag-major byte offset for element (m,k) of a [64 m][K k] activation
DEVI u32 fragoff(int m, int k) {
  return (u32)((((k >> 5) * 4 + (m >> 4)) * 64 + ((k >> 3) & 3) * 16 + (m & 15)) * 16 + (k & 7) * 2);
}
// per-step slot addressing (slot 0 = initial state, slot t+1 = written at step t)
DEVI char* of_slot(char* w, int s) { return w + (s ? OFR_O + (long)(s - 1) * 131072 : OF0_O); }
DEVI char* h0_slot(char* w, int s) { return w + (s ? H0R_O + (long)(s - 1) * 131072 : H00_O); }
DEVI char* h1_slot(char* w, int s) { return w + (s ? H1R_O + (long)(s - 1) * 131072 : H10_O); }

// ---------------- barriers ----------------
// arrive: flag store per block.  wait: aggregator block (128) polls all flags
// then broadcasts one generation word; everyone else polls that single line.
DEVI void pollflags(u32* flags, u32 gen) {
  int t = threadIdx.x;   // < 64
  for (;;) {
    u32 a = __hip_atomic_load(&flags[t],       __ATOMIC_RELAXED, __HIP_MEMORY_SCOPE_AGENT);
    u32 b = __hip_atomic_load(&flags[64 + t],  __ATOMIC_RELAXED, __HIP_MEMORY_SCOPE_AGENT);
    u32 c = __hip_atomic_load(&flags[128 + t], __ATOMIC_RELAXED, __HIP_MEMORY_SCOPE_AGENT);
    u32 d = __hip_atomic_load(&flags[192 + t], __ATOMIC_RELAXED, __HIP_MEMORY_SCOPE_AGENT);
    if (__all((a >= gen) && (b >= gen) && (c >= gen) && (d >= gen))) break;
  }
}
DEVI void barr_arrive(u32* flags, u32 gen) {
  VMFLUSH();               // drain sc stores to LLC before signaling
  __syncthreads();
  if (threadIdx.x == 0)
    __hip_atomic_store(&flags[blockIdx.x], gen, __ATOMIC_RELAXED, __HIP_MEMORY_SCOPE_AGENT);
}
DEVI void barr_wait(u32* flags, u32 gen) {
  u32* bc = flags + 320;   // broadcast word, own cache line
  if (blockIdx.x == 128) {
    if (threadIdx.x < 64) pollflags(flags, gen);
    __syncthreads();
    if (threadIdx.x == 0)
      __hip_atomic_store(bc, gen, __ATOMIC_RELAXED, __HIP_MEMORY_SCOPE_AGENT);
  } else {
    if (threadIdx.x == 0) {
      while (__hip_atomic_load(bc, __ATOMIC_RELAXED, __HIP_MEMORY_SCOPE_AGENT) < gen) {}
    }
  }
  __syncthreads();
  asm volatile("" ::: "memory");
}
// fenced barrier (setup only; all-to-all is fine twice)
DEVI void gsync_fence(u32* flags, u32 gen) {
  __syncthreads();
  if (threadIdx.x == 0) {
    __builtin_amdgcn_fence(__ATOMIC_RELEASE, "agent");
    __hip_atomic_store(&flags[blockIdx.x], gen, __ATOMIC_RELAXED, __HIP_MEMORY_SCOPE_AGENT);
  }
  if (threadIdx.x < 64) pollflags(flags, gen);
  if (threadIdx.x == 0) __builtin_amdgcn_fence(__ATOMIC_ACQUIRE, "agent");
  __syncthreads();
}

// ---------------- gate-GEMM segment: cached loads, compiler-pipelined ----------------
template<int N4>
DEVI void gseg(f32x4& acc, const char* Af, int kkA0, int mt, int lane,
               const char* W, int wRowK, int kkW0, int brow, int ke) {
  const u32 sw = (u32)((brow & 7) << 4);
#pragma unroll
  for (int g = 0; g < N4; ++g) {
#pragma unroll
    for (int q = 0; q < 4; ++q) {
      const char* pa = Af + ((((kkA0 + g * 4 + q) * 4 + mt) * 64 + lane) << 4);
      bfrag av = *(const bfrag*)pa;
      int kkW = kkW0 + g * 4 + q;
      u32 off = ((u32)(brow * wRowK + kkW * 32 + ke) * 2) ^ sw;
      acc = mfma16(av, *(const bfrag*)(W + off), acc);
    }
  }
}

DEVI void scr_store(float* scr, int slot, f32x4 acc) {
  const int lane = threadIdx.x & 63;
#pragma unroll
  for (int r = 0; r < 4; ++r)
    scr[slot * 272 + ((lane >> 4) * 4 + r) * 17 + (lane & 15)] = acc[r];
}

// LSTM pointwise: threads 0..63; c-state in registers; one 8B sc h-store
DEVI void pointwise64(int bid, const float* scr, const float* bias, float (&cst)[4], char* hfrag) {
  const int m = threadIdx.x;            // < 64
  const int mt = m >> 4, ml = m & 15;
  u32 hp0 = 0, hp1 = 0;
#pragma unroll
  for (int u = 0; u < 4; ++u) {
    const int j = bid * 4 + u;
    float g0 = scr[(mt*2)*272 + ml*17 + u]      + scr[(mt*2+1)*272 + ml*17 + u]      + bias[j];
    float g1 = scr[(mt*2)*272 + ml*17 + 4 + u]  + scr[(mt*2+1)*272 + ml*17 + 4 + u]  + bias[1024 + j];
    float g2 = scr[(mt*2)*272 + ml*17 + 8 + u]  + scr[(mt*2+1)*272 + ml*17 + 8 + u]  + bias[2048 + j];
    float g3 = scr[(mt*2)*272 + ml*17 + 12 + u] + scr[(mt*2+1)*272 + ml*17 + 12 + u] + bias[3072 + j];
    float cn = sigm(g1) * cst[u] + sigm(g0) * tanh_(g2);
    cst[u] = cn;
    u32 hb = (u32)f2bf(sigm(g3) * tanh_(cn));
    if (u == 0) hp0 = hb; else if (u == 1) hp0 |= hb << 16;
    else if (u == 2) hp1 = hb; else hp1 |= hb << 16;
  }
  u32x2 v; v[0] = hp0; v[1] = hp1;
  ST8SC(hfrag + fragoff(m, bid * 4), v);
}

// copy-attention for one (batch, step): scores from global CtxWc, softmax, AC out
DEVI void copyattn_step(int b, int tau, const u16* CtxWc, const float* outp,
                        float* xch, float* dout) {
  const int tid = threadIdx.x, lane = tid & 63, w = tid >> 6;
  float ov[16];
  {
    const float4* op = (const float4*)(outp + (long)tau * 65536 + b * 1024 + lane * 16);
#pragma unroll
    for (int i = 0; i < 4; ++i) {
      float4 v = op[i];
      ov[4 * i] = v.x; ov[4 * i + 1] = v.y; ov[4 * i + 2] = v.z; ov[4 * i + 3] = v.w;
    }
  }
  const u16* cwb = CtxWc + (long)b * 65536;
#pragma unroll
  for (int si = 0; si < 8; ++si) {
    int s = w * 8 + si;
    const u32* u = (const u32*)(cwb + (long)s * 1024 + lane * 16);
    float acc = 0.f;
#pragma unroll
    for (int i = 0; i < 8; ++i) {
      u32 x = u[i];
      acc += ov[2 * i] * bf2f((u16)(x & 0xffff));
      acc += ov[2 * i + 1] * bf2f((u16)(x >> 16));
    }
#pragma unroll
    for (int off = 32; off; off >>= 1) acc += __shfl_down(acc, off, 64);
    if (lane == 0) xch[s] = acc;
  }
  __syncthreads();
  if (w == 0) {
    float v = xch[lane];
    float mx = v;
#pragma unroll
    for (int off = 32; off; off >>= 1) mx = fmaxf(mx, __shfl_xor(mx, off, 64));
    float e = __expf(v - mx);
    float sm = e;
#pragma unroll
    for (int off = 32; off; off >>= 1) sm += __shfl_xor(sm, off, 64);
    dout[AC_OFF + (long)tau * 4096 + b * 64 + lane] = e / sm;
  }
  // caller must __syncthreads() before reusing xch (P4c does)
}

// setup GEMMs (sc stores)
DEVI void ctxw_gemm(int mt, const u16* Ctx, const u16* Wm, u16* dst) {
  const int tid = threadIdx.x, lane = tid & 63, w = tid >> 6;
  const int arow = mt * 16 + (lane & 15);
  const int ke = (lane >> 4) * 8;
#pragma unroll
  for (int i = 0; i < 8; ++i) {
    int nt = w * 8 + i;
    const u16* A = Ctx + (long)arow * 1024 + ke;
    const u16* B = Wm + (long)(nt * 16 + (lane & 15)) * 1024 + ke;
    f32x4 acc = {0.f, 0.f, 0.f, 0.f};
    for (int kk = 0; kk < 1024; kk += 32)
      acc = mfma16(*(const bfrag*)(A + kk), *(const bfrag*)(B + kk), acc);
#pragma unroll
    for (int r = 0; r < 4; ++r)
      ST2SC((char*)(dst + (long)(mt * 16 + (lane >> 4) * 4 + r) * 1024 + nt * 16 + (lane & 15)),
            (u32)f2bf(acc[r]));
  }
}
DEVI void ctxo_gemm(int bid, const u16* Ctx, const u16* Wao, u16* dst) {
  const int tid = threadIdx.x, lane = tid & 63, w = tid >> 6;
  const int arow = bid * 16 + (lane & 15);
  const int ke = (lane >> 4) * 8;
  const int b = bid >> 2, s0 = (bid & 3) * 16 + (lane >> 4) * 4;
#pragma unroll
  for (int i = 0; i < 8; ++i) {
    int nt = w * 8 + i;
    int j = nt * 16 + (lane & 15);
    const u16* A = Ctx + (long)arow * 1024 + ke;
    const u16* B = Wao + (long)j * 2048 + ke;
    f32x4 acc = {0.f, 0.f, 0.f, 0.f};
    for (int kk = 0; kk < 1024; kk += 32)
      acc = mfma16(*(const bfrag*)(A + kk), *(const bfrag*)(B + kk), acc);
    u32x2 q;
    q[0] = (u32)f2bf(acc[0]) | ((u32)f2bf(acc[1]) << 16);
    q[1] = (u32)f2bf(acc[2]) | ((u32)f2bf(acc[3]) << 16);
    ST8SC((char*)(dst + ((long)(b * 1024 + j) * 64 + s0)), q);
  }
}

// ---------------- the kernel ----------------
__global__ __launch_bounds__(512, 1) void decoder_kernel(KParams p) {
  extern __shared__ char smem[];
  char*  W0   = smem + W0LDS_O;
  char*  W1   = smem + W1LDS_O;
  float* scr  = (float*)(smem + SCR_O);
  float* scr2 = (float*)(smem + SCR2_O);

  char* wsb = p.ws;
  u16* Wao   = (u16*)(wsb + WAO_O);
  u16* Wai   = (u16*)(wsb + WAI_O);
  u16* Wc    = (u16*)(wsb + WC_O);
  u16* Ctx   = (u16*)(wsb + CTX_O);
  u16* CtxW  = (u16*)(wsb + CTXW_O);
  u16* CtxWc = (u16*)(wsb + CTXWC_O);
  u16* CtxOT = (u16*)(wsb + CTXOT_O);
  u32* bar   = (u32*)(wsb + BAR_O);

  const int bid = blockIdx.x, tid = threadIdx.x;
  const int lane = tid & 63, w = tid >> 6;
  const long gtid = (long)bid * 512 + tid, NT = 256l * 512;
  u32 gen = 1;

  // ---- S0-pre: LDS-tiled transposes of attn_in / copy_in (sc out) ----
  {
    float* tile = (float*)smem;
    for (int pass = 0; pass < 2; ++pass) {
      const float* src = pass ? p.copy_in : p.attn_in;
      u16* dst = pass ? Wc : Wai;
      int tr = bid >> 4, tc = bid & 15;
      {
        int r = tid >> 3, c = (tid & 7) * 8;
        const float4* s4 = (const float4*)(src + (long)(tr * 64 + r) * 1024 + tc * 64 + c);
        float4 a = s4[0], b = s4[1];
        float* tp = tile + r * 69 + c;
        tp[0] = a.x; tp[1] = a.y; tp[2] = a.z; tp[3] = a.w;
        tp[4] = b.x; tp[5] = b.y; tp[6] = b.z; tp[7] = b.w;
      }
      __syncthreads();
      {
        int r2 = tid >> 3, c2 = (tid & 7) * 8;
        u32x4 q;
#pragma unroll
        for (int i = 0; i < 4; ++i) {
          float lo = tile[(c2 + 2 * i) * 69 + r2];
          float hi = tile[(c2 + 2 * i + 1) * 69 + r2];
          q[i] = (u32)f2bf(lo) | ((u32)f2bf(hi) << 16);
        }
        ST16SC((char*)(dst + (long)(tc * 64 + r2) * 1024 + tr * 64 + c2), q);
      }
      __syncthreads();
    }
  }

  // ---- S0a: per-block weight slices -> LDS (stationary all 32 steps) ----
  for (int i = tid; i < 5120; i += 512) {
    int row = i / 320, k = (i % 320) * 8;
    int R = (row >> 2) * 1024 + bid * 4 + (row & 3);
    const float* src = (k < 1536) ? (p.W_ih0 + (long)R * 1536 + k)
                                  : (p.W_hh0 + (long)R * 1024 + (k - 1536));
    float4 a = *(const float4*)src, b = *(const float4*)(src + 4);
    uint4 q;
    q.x = (u32)f2bf(a.x) | ((u32)f2bf(a.y) << 16);
    q.y = (u32)f2bf(a.z) | ((u32)f2bf(a.w) << 16);
    q.z = (u32)f2bf(b.x) | ((u32)f2bf(b.y) << 16);
    q.w = (u32)f2bf(b.z) | ((u32)f2bf(b.w) << 16);
    u32 off = ((u32)(row * 2560 + k) * 2) ^ ((u32)((row & 7) << 4));
    *(uint4*)(W0 + off) = q;
  }
  for (int i = tid; i < 4096; i += 512) {
    int row = i / 256, k = (i % 256) * 8;
    int R = (row >> 2) * 1024 + bid * 4 + (row & 3);
    const float* src = (k < 1024) ? (p.W_ih1 + (long)R * 1024 + k)
                                  : (p.W_hh1 + (long)R * 1024 + (k - 1024));
    float4 a = *(const float4*)src, b = *(const float4*)(src + 4);
    uint4 q;
    q.x = (u32)f2bf(a.x) | ((u32)f2bf(a.y) << 16);
    q.y = (u32)f2bf(a.z) | ((u32)f2bf(a.w) << 16);
    q.z = (u32)f2bf(b.x) | ((u32)f2bf(b.y) << 16);
    q.w = (u32)f2bf(b.z) | ((u32)f2bf(b.w) << 16);
    u32 off = ((u32)(row * 2048 + k) * 2) ^ ((u32)((row & 7) << 4));
    *(uint4*)(W1 + off) = q;
  }

  // ---- S0b: global conversions (all sc stores) ----
  for (long i = gtid; i < 524288; i += NT) cvtc_sc(p.attn_out + i * 4, (char*)(Wao + i * 4));
  for (long i = gtid; i < 1048576; i += NT) {
    long b = i >> 14, s = (i >> 8) & 63, kq = i & 255;
    cvtc_sc(p.context + ((s * 64 + b) * 1024 + kq * 4), (char*)(Ctx + i * 4));
  }
  for (long i = gtid; i < 262144; i += NT) {     // emb gather -> frag-major
    long row = i >> 7; long t = row >> 6, b = row & 63;
    long k0 = (i & 127) * 4;
    long tok = p.input[row];
    cvtc_sc(p.embedding + tok * 512 + k0, wsb + EBF_O + t * 65536 + fragoff((int)b, (int)k0));
  }
  for (long i = gtid; i < 16384; i += NT) {      // init_output -> OF slot 0
    long b = i >> 8, k0 = (i & 255) * 4;
    cvtc_sc(p.init_output + i * 4, of_slot(wsb, 0) + fragoff((int)b, (int)k0));
  }
  for (long i = gtid; i < 32768; i += NT) {      // h0 -> h slots 0
    long l = i >> 14, rem = i & 16383, b = rem >> 8, k0 = (rem & 255) * 4;
    cvtc_sc(p.h0 + i * 4, (l ? h1_slot(wsb, 0) : h0_slot(wsb, 0)) + fragoff((int)b, (int)k0));
  }

  // ---- c-state -> registers (threads 0..63; thread m owns (m, j=bid*4+u)) ----
  float cR0[4] = {0.f, 0.f, 0.f, 0.f}, cR1[4] = {0.f, 0.f, 0.f, 0.f};
  if (tid < 64) {
#pragma unroll
    for (int u = 0; u < 4; ++u) {
      cR0[u] = p.c0[(long)tid * 1024 + bid * 4 + u];
      cR1[u] = p.c0[65536 + (long)tid * 1024 + bid * 4 + u];
    }
  }

  gsync_fence(bar, gen); ++gen;

  // ---- S1: attention tables ----
  ctxw_gemm(bid, Ctx, Wai, CtxW);
  ctxw_gemm(bid, Ctx, Wc, CtxWc);
  ctxo_gemm(bid, Ctx, Wao, CtxOT);
  gsync_fence(bar, gen); ++gen;

  // ---- P4 geometry (XCD-pinned) + Wao h1-half fragments in registers ----
  const int xcd = bid & 7, idx = bid >> 3;
  const int ntP4 = xcd * 8 + (idx & 7), mtP4 = idx >> 3;
  const int browP4 = ntP4 * 16 + (lane & 15);
  const int ke_ = (lane >> 4) * 8;
  bfrag waoreg[4];
#pragma unroll
  for (int q = 0; q < 4; ++q)
    waoreg[q] = *(const bfrag*)(Wao + (long)browP4 * 2048 + 1024 + (w * 4 + q) * 32 + ke_);

  const int mt_ = w & 3, kh_ = w >> 2;
  const int brow_ = lane & 15;

  // ---- pre-loop P1(0) lookahead: emb(0) + h0 slot 0 ----
  f32x4 accP1 = {0.f, 0.f, 0.f, 0.f}, accP2;
  {
    const char* E0  = wsb + EBF_O;
    const char* H0p = h0_slot(wsb, 0);
    if (kh_ == 0) {
      gseg<2>(accP1, E0,  0,  mt_, lane, W0, 2560, 0,  brow_, ke_);
      gseg<4>(accP1, H0p, 0,  mt_, lane, W0, 2560, 48, brow_, ke_);
    } else {
      gseg<2>(accP1, E0,  8,  mt_, lane, W0, 2560, 8,  brow_, ke_);
      gseg<4>(accP1, H0p, 16, mt_, lane, W0, 2560, 64, brow_, ke_);
    }
  }

  for (int t = 0; t < 32; ++t) {
    const char* OFc   = of_slot(wsb, t);
    char*       Hb0cF = h0_slot(wsb, t + 1);
    char*       Hb1cF = h1_slot(wsb, t + 1);
    const char* Hb1pF = h1_slot(wsb, t);
    char*       ABt   = wsb + AB_O + (long)t * 16384;

    // ---- P1 remainder: out-feed segment ----
    {
      f32x4 acc = accP1;
      if (kh_ == 0) gseg<4>(acc, OFc, 0,  mt_, lane, W0, 2560, 16, brow_, ke_);
      else          gseg<4>(acc, OFc, 16, mt_, lane, W0, 2560, 32, brow_, ke_);
      scr_store(scr, mt_ * 2 + kh_, acc);
      __syncthreads();
      if (tid < 64) pointwise64(bid, scr, p.b0, cR0, Hb0cF);
    }
    barr_arrive(bar, gen);
    // P2 lookahead: h1prev segment
    accP2 = f32x4{0.f, 0.f, 0.f, 0.f};
    if (kh_ == 0) gseg<4>(accP2, Hb1pF, 0,  mt_, lane, W1, 2048, 32, brow_, ke_);
    else          gseg<4>(accP2, Hb1pF, 16, mt_, lane, W1, 2048, 48, brow_, ke_);
    barr_wait(bar, gen); ++gen;

    // ---- P2 remainder: h0new segment ----
    {
      f32x4 acc = accP2;
      if (kh_ == 0) gseg<4>(acc, Hb0cF, 0,  mt_, lane, W1, 2048, 0,  brow_, ke_);
      else          gseg<4>(acc, Hb0cF, 16, mt_, lane, W1, 2048, 16, brow_, ke_);
      scr_store(scr, mt_ * 2 + kh_, acc);
      __syncthreads();
      if (tid < 64) pointwise64(bid, scr, p.b1, cR1, Hb1cF);
    }
    barr_arrive(bar, gen);
    // P1(t+1) lookahead part A: emb(t+1) + first half of h0(t+1)
    accP1 = f32x4{0.f, 0.f, 0.f, 0.f};
    {
      const char* En = wsb + EBF_O + (long)((t + 1) & 31) * 65536;
      if (kh_ == 0) {
        gseg<2>(accP1, En,    0,  mt_, lane, W0, 2560, 0,  brow_, ke_);
        gseg<2>(accP1, Hb0cF, 0,  mt_, lane, W0, 2560, 48, brow_, ke_);
      } else {
        gseg<2>(accP1, En,    8,  mt_, lane, W0, 2560, 8,  brow_, ke_);
        gseg<2>(accP1, Hb0cF, 16, mt_, lane, W0, 2560, 64, brow_, ke_);
      }
    }
    barr_wait(bar, gen); ++gen;

    // ---- P3 (blocks 0..63): scores + softmax -> a(t) + per-batch ready flag ----
    if (bid < 64) {
      const int b = bid;
      float h1v[16];
      {
        int k0 = lane * 16;
        const u32* hp0 = (const u32*)(Hb1cF + fragoff(b, k0));
        const u32* hp1 = (const u32*)(Hb1cF + fragoff(b, k0 + 8));
        u32 uu[8] = {hp0[0], hp0[1], hp0[2], hp0[3], hp1[0], hp1[1], hp1[2], hp1[3]};
#pragma unroll
        for (int i = 0; i < 8; ++i) {
          h1v[2 * i]     = bf2f((u16)(uu[i] & 0xffff));
          h1v[2 * i + 1] = bf2f((u16)(uu[i] >> 16));
        }
      }
      const u16* cwb = CtxW + (long)b * 65536;
#pragma unroll
      for (int si = 0; si < 8; ++si) {
        int s = w * 8 + si;
        const u32* u = (const u32*)(cwb + (long)s * 1024 + lane * 16);
        float acc = 0.f;
#pragma unroll
        for (int i = 0; i < 8; ++i) {
          u32 x = u[i];
          acc += h1v[2 * i] * bf2f((u16)(x & 0xffff));
          acc += h1v[2 * i + 1] * bf2f((u16)(x >> 16));
        }
#pragma unroll
        for (int off = 32; off; off >>= 1) acc += __shfl_down(acc, off, 64);
        if (lane == 0) scr2[s] = acc;
      }
      __syncthreads();
      if (w == 0) {
        float v = scr2[lane];
        float mx = v;
#pragma unroll
        for (int off = 32; off; off >>= 1) mx = fmaxf(mx, __shfl_xor(mx, off, 64));
        float e = __expf(v - mx);
        float sm = e;
#pragma unroll
        for (int off = 32; off; off >>= 1) sm += __shfl_xor(sm, off, 64);
        float a = e / sm;
        ST4SC(ABt + (u32)(b * 64 + lane) * 4, __builtin_bit_cast(u32, a));
        ST4SC((char*)(p.out + AS_OFF + (long)t * 4096 + b * 64 + lane), __builtin_bit_cast(u32, a));
        VMFLUSH();   // a-values at LLC before ready flag
        if (lane == 0)
          ST4SC(wsb + AFLAG_O + ((u32)t * 64 + b) * 4, 1u);
      }
    }
    // P4h: h1-half of out-projection (all blocks, 8-way K-split)
    {
      const char* bp = Hb1cF;
      bfrag h0_ = *(const bfrag*)(bp + ((((w * 4 + 0) * 4 + mtP4) * 64 + lane) << 4));
      bfrag h1_ = *(const bfrag*)(bp + ((((w * 4 + 1) * 4 + mtP4) * 64 + lane) << 4));
      bfrag h2_ = *(const bfrag*)(bp + ((((w * 4 + 2) * 4 + mtP4) * 64 + lane) << 4));
      bfrag h3_ = *(const bfrag*)(bp + ((((w * 4 + 3) * 4 + mtP4) * 64 + lane) << 4));
      f32x4 a4 = {0.f, 0.f, 0.f, 0.f};
      a4 = mfma16(h0_, waoreg[0], a4);
      a4 = mfma16(h1_, waoreg[1], a4);
      a4 = mfma16(h2_, waoreg[2], a4);
      a4 = mfma16(h3_, waoreg[3], a4);
      scr_store(scr, w, a4);
    }
    // in-loop copy-attention for step t-1 (blocks 192..255, otherwise idle here)
    if (bid >= 192 && t > 0)
      copyattn_step(bid - 192, t - 1, CtxWc, p.out, scr2, p.out);

    // ---- P4c: prefetch CtxOT -> regs, poll a-ready flags, then combine ----
    {
      const int pair = tid >> 1, half = tid & 1;
      const int m_l = pair >> 4, j_l = pair & 15;
      const int b = mtP4 * 16 + m_l, j = ntP4 * 16 + j_l;
      u32 cpr[16];
      {
        const u32* cp = (const u32*)(CtxOT + ((long)(b * 1024 + j) * 64 + half * 32));
#pragma unroll
        for (int i = 0; i < 16; ++i) cpr[i] = cp[i];
      }
      if (tid < 16) {
        const u32* fp = (const u32*)(wsb + AFLAG_O + ((u32)t * 64 + mtP4 * 16 + tid) * 4);
        while (__hip_atomic_load(fp, __ATOMIC_RELAXED, __HIP_MEMORY_SCOPE_AGENT) == 0) {}
      }
      __syncthreads();
      {
        int b0i = tid >> 6, s0i = tid & 63;
        int b1i = (tid + 512) >> 6;
        scr2[tid]       = *(const float*)(ABt + (u32)(((mtP4 * 16 + b0i) * 64 + s0i)) * 4);
        scr2[tid + 512] = *(const float*)(ABt + (u32)(((mtP4 * 16 + b1i) * 64 + s0i)) * 4);
      }
      __syncthreads();
      const float* al = scr2 + m_l * 64 + half * 32;
      float acc = 0.f;
#pragma unroll
      for (int i = 0; i < 16; ++i) {
        u32 x = cpr[i];
        acc += al[2 * i] * bf2f((u16)(x & 0xffff));
        acc += al[2 * i + 1] * bf2f((u16)(x >> 16));
      }
      float v = acc + __shfl_xor(acc, 1, 64);
      if (half == 0) {
        float h1p = 0.f;
#pragma unroll
        for (int q = 0; q < 8; ++q) h1p += scr[q * 272 + m_l * 17 + j_l];
        v = tanh_(v + h1p);
        ST4SC((char*)(p.out + (long)t * 65536 + b * 1024 + j), __builtin_bit_cast(u32, v));
        u32 hv = (u32)f2bf(v);
        ST2SC(of_slot(wsb, t + 1) + fragoff(b, j), hv);
      }
    }
    barr_arrive(bar, gen);
    // P1(t+1) lookahead part B: second half of h0(t+1)
    if (kh_ == 0) gseg<2>(accP1, Hb0cF, 8,  mt_, lane, W0, 2560, 56, brow_, ke_);
    else          gseg<2>(accP1, Hb0cF, 24, mt_, lane, W0, 2560, 72, brow_, ke_);
    barr_wait(bar, gen); ++gen;
  }

  // ---- epilogue: final states (slot 32; h from frag, c from registers) ----
  if (tid < 64) {
#pragma unroll
    for (int u = 0; u < 4; ++u) {
      int j = bid * 4 + u;
      p.out[CT_OFF + (long)tid * 1024 + j]         = cR0[u];
      p.out[CT_OFF + 65536 + (long)tid * 1024 + j] = cR1[u];
    }
  }
  if (tid < 256) {
    int u = tid >> 6, m = tid & 63, j = bid * 4 + u;
    u16 a0 = *(const u16*)(h0_slot(wsb, 32) + fragoff(m, j));
    u16 a1 = *(const u16*)(h1_slot(wsb, 32) + fragoff(m, j));
    p.out[HT_OFF + (long)m * 1024 + j]         = bf2f(a0);
    p.out[HT_OFF + 65536 + (long)m * 1024 + j] = bf2f(a1);
  }

  // ---- final copy-attention step (tau = 31, blocks 192..255) ----
  if (bid >= 192) {
    __syncthreads();
    copyattn_step(bid - 192, 31, CtxWc, p.out, scr2, p.out);
  }
}

// ---------------- host ----------------
extern "C" void kernel_launch(void* const* d_in, const int* in_sizes, int n_in,
                              void* d_out, int out_size, void* d_ws, size_t ws_size,
                              hipStream_t stream) {
  KParams p;
  p.input       = (const int*)d_in[0];
  p.h0          = (const float*)d_in[1];
  p.c0          = (const float*)d_in[2];
  p.context     = (const float*)d_in[3];
  p.init_output = (const float*)d_in[4];
  p.embedding   = (const float*)d_in[5];
  p.W_ih0       = (const float*)d_in[6];
  p.W_hh0       = (const float*)d_in[7];
  p.b0          = (const float*)d_in[8];
  p.W_ih1       = (const float*)d_in[9];
  p.W_hh1       = (const float*)d_in[10];
  p.b1          = (const float*)d_in[11];
  p.attn_in     = (const float*)d_in[12];
  p.attn_out    = (const float*)d_in[13];
  p.copy_in     = (const float*)d_in[14];
  p.out         = (float*)d_out;
  p.ws          = (char*)d_ws;

  (void)hipFuncSetAttribute((const void*)decoder_kernel,
                            hipFuncAttributeMaxDynamicSharedMemorySize, 160256);
  // zero: a-buffer (512KB) + a-ready flags (8KB) + barrier flags/bcast (2KB)
  (void)hipMemsetAsync((char*)d_ws + AB_O, 0, 534528, stream);
  void* args[] = { &p };
  (void)hipLaunchCooperativeKernel((void*)decoder_kernel, dim3(256), dim3(512),
                                   args, 160256, stream);
}